// Round 9
// baseline (315.385 us; speedup 1.0000x reference)
//
#include <hip/hip_runtime.h>
#include <cstdint>
#include <cstddef>

#define NQT   150
#define WAYT  5
#define CCH   640

typedef _Float16 f16;
typedef _Float16 f16x2 __attribute__((ext_vector_type(2)));
typedef _Float16 f16x4 __attribute__((ext_vector_type(4)));
typedef _Float16 f16x8 __attribute__((ext_vector_type(8)));
typedef float    f32x4 __attribute__((ext_vector_type(4)));

static __device__ __forceinline__ f16x2 pkrtz(float a, float b){
  return __builtin_bit_cast(f16x2, __builtin_amdgcn_cvt_pkrtz(a, b));
}

// const-pack offsets (floats)
#define CP_A     0
#define CP_B     16
#define CP_G2    32
#define CP_B2    48
#define CP_W20   64
#define CP_W10   73
#define CP_SC    82
#define CP_T9    96
#define GS_STRIDE 1076

// stencil matrix value: Mat[k = src pos][n = dst pos], 10x10 grid, 3x3 taps
static __device__ __forceinline__ float stencil9(int k, int n, const float* __restrict__ w9){
  if (k >= 100 || n >= 100) return 0.f;
  const int a = n/10, b = n%10, a2 = k/10, b2 = k%10;
  const int dA = a2 - a + 1, dB = b2 - b + 1;
  if ((unsigned)dA > 2u || (unsigned)dB > 2u) return 0.f;
  return w9[dA*3 + dB];
}

// ---------------- prep (merged; grid 241) ----------------
__global__ __launch_bounds__(256) void k_prep_all(
    const float* __restrict__ spt, const float* __restrict__ W,
    const float* __restrict__ s0_w2, const float* __restrict__ s0_g2, const float* __restrict__ s0_b2,
    const float* __restrict__ s0_w1, const float* __restrict__ s0_g1, const float* __restrict__ s0_b1,
    const float* __restrict__ s0_wp, const float* __restrict__ s0_gp, const float* __restrict__ s0_bp,
    const float* __restrict__ s1_w2, const float* __restrict__ s1_g2, const float* __restrict__ s1_b2,
    const float* __restrict__ s1_w1, const float* __restrict__ s1_g1, const float* __restrict__ s1_b1,
    const float* __restrict__ s1_wp, const float* __restrict__ s1_gp, const float* __restrict__ s1_bp,
    float* __restrict__ cp, f16* __restrict__ Apack, f16* __restrict__ Wf2, f16* __restrict__ Wf8,
    f16* __restrict__ MuF, f16* __restrict__ MhF,
    f16* __restrict__ W65, float* __restrict__ wsum, f16* __restrict__ spt16)
{
  const int b = blockIdx.x, t = threadIdx.x;
  if (b == 0){
    for (int e = t; e < 2560; e += 256){
      int p = e / 512, r = e % 512, l = r / 8, j = r % 8;
      int kb = l >> 4;
      int tap = 2*p + (kb >> 1);
      int cin = (kb & 1)*8 + j;
      int co = l & 15;
      float v = 0.f;
      if (tap <= 8){
        int du = tap / 3, dv = tap % 3;
        v = s1_w2[((co*16 + cin)*3 + du)*3 + dv];
      }
      Apack[e] = (f16)v;
    }
    const float gp1 = s1_gp[0];
    {
      int l = t >> 2, j = t & 3;
      int tap = l & 15, ci = ((l >> 4) << 2) + j;
      float v = 0.f;
      if (tap <= 8){
        for (int co = 0; co < 16; co++)
          v += gp1 * s1_wp[co] * s1_g1[co] * s1_w1[(co*16 + ci)*9 + tap];
      }
      Wf2[t] = (f16)v;
    }
    {
      // Wf8: A-frag 16x16x16 for tap 8 (du=2,dv=2): A[co][cin]
      int l = t >> 2, j = t & 3;
      int co = l & 15, cin = ((l >> 4) << 2) + j;
      Wf8[t] = (f16)s1_w2[((co*16 + cin)*3 + 2)*3 + 2];
    }
    if (t < 144){
      int tap = t / 16, co = t % 16;
      float s = 0.f;
      for (int cin = 0; cin < 16; cin++){
        float wv = (float)(f16)s1_w2[((co*16 + cin)*3 + tap/3)*3 + tap%3];
        float rb = fmaxf((float)(f16)s0_bp[cin], 0.f);
        s += wv * rb;
      }
      cp[CP_T9 + t] = s;
    }
    if (t < 16){
      cp[CP_A + t]  = s0_gp[t] * s0_wp[t];
      cp[CP_B + t]  = s0_bp[t];
      cp[CP_G2 + t] = s1_g2[t];
      cp[CP_B2 + t] = s1_b2[t];
    }
    if (t < 9){ cp[CP_W20 + t] = s0_w2[t]; cp[CP_W10 + t] = s0_w1[t]; }
    if (t == 0){
      cp[CP_SC + 0] = s0_g2[0]; cp[CP_SC + 1] = s0_b2[0];
      cp[CP_SC + 2] = s0_g1[0]; cp[CP_SC + 3] = s0_b1[0];
      float kk = 0.f;
      for (int co = 0; co < 16; co++) kk += s1_wp[co] * s1_b1[co];
      cp[CP_SC + 4] = gp1 * kk + s1_bp[0];
    }
  } else if (b <= 14){
    const bool isMu = (b <= 7);
    f16* dst = isMu ? MuF : MhF;
    const float* w9 = isMu ? s0_w2 : s0_w1;
    const int base = (isMu ? (b-1) : (b-8)) * 2048;
    #pragma unroll
    for (int e2 = 0; e2 < 8; e2++){
      const int idx = base + e2*256 + t;
      const int j = idx & 7, l2 = (idx >> 3) & 63, ktnt = idx >> 9;
      const int kt = ktnt & 3, nt = ktnt >> 2;
      const int n = nt*16 + (l2 & 15);
      const int k = kt*32 + ((l2 >> 4) & 3)*8 + j;
      dst[idx] = (f16)stencil9(k, n, w9);
    }
  } else if (b <= 39){
    const int base = (b - 15) * 2048;
    #pragma unroll
    for (int e2 = 0; e2 < 8; e2++){
      const int idx = base + e2*256 + t;
      const int row = idx / 640, c = idx - row*640;
      float v = 0.f;
      if (row < 64) v = W[row*640 + c];
      else if (row == 64) v = 1.f;
      W65[idx] = (f16)v;
    }
  } else if (b == 40){
    const int o = t >> 2, qq = t & 3;
    float s = 0.f;
    for (int c = qq; c < 640; c += 4) s += W[o*640 + c];
    s += __shfl_xor(s, 1); s += __shfl_xor(s, 2);
    if (qq == 0) wsum[o] = s;
  } else {
    // spt16: [5][640][128] f16, k>=100 zero
    const int base = (b - 41) * 2048;
    #pragma unroll
    for (int e2 = 0; e2 < 8; e2++){
      const int idx = base + e2*256 + t;
      const int w = idx / 81920, r = idx % 81920;
      const int c = r >> 7, k = r & 127;
      spt16[idx] = (k < 100) ? (f16)spt[(size_t)w*64000 + c*100 + k] : (f16)0;
    }
  }
}

// ---------------- feat: 620 blocks; GEMM Y[80][32] per block ----------------
__device__ __forceinline__ void feat_stage4(const float* __restrict__ x, int pixoff, int kt,
                                            f16* __restrict__ dst, int t){
  if (t < 224){
    const int cc = t / 7, qd = t % 7;
    float4 v4 = make_float4(0.f, 0.f, 0.f, 0.f);
    if (pixoff + qd*4 + 4 <= 100)
      v4 = *(const float4*)(x + (size_t)(kt*32 + cc)*100 + pixoff + qd*4);
    dst[(qd*4+0)*40 + cc] = (f16)v4.x;
    dst[(qd*4+1)*40 + cc] = (f16)v4.y;
    dst[(qd*4+2)*40 + cc] = (f16)v4.z;
    dst[(qd*4+3)*40 + cc] = (f16)v4.w;
  }
}

__global__ __launch_bounds__(256) void k_feat(
    const float* __restrict__ spt, const float* __restrict__ qry,
    const f16* __restrict__ W65, const float* __restrict__ wsum,
    const float* __restrict__ gg, const float* __restrict__ bb,
    f16* __restrict__ s16, f16* __restrict__ q16,
    float* __restrict__ sptm, float* __restrict__ qrym)
{
  __shared__ f16 Xs[2][32*40];
  __shared__ float Ys[32*85];
  __shared__ float sg[64], sb[64], sw[64];
  const int b = blockIdx.x;
  const int n = b >> 2, quarter = b & 3;
  const int pixbase = quarter * 28;
  const float* x; f16* out16; float* mout;
  if (n < 5){ x = spt + (size_t)n*64000; out16 = s16 + (size_t)n*7168; mout = sptm + n*100; }
  else { x = qry + (size_t)(n-5)*64000; out16 = q16 + (size_t)(n-5)*7168; mout = qrym + (size_t)(n-5)*100; }
  const int t = threadIdx.x, l = t & 63, wid = t >> 6;
  const int r16 = l & 15, kbq = (l >> 4) & 3;

  if (t < 40){
    const f16x8 z8 = {(f16)0,(f16)0,(f16)0,(f16)0,(f16)0,(f16)0,(f16)0,(f16)0};
    const int bu = t / 20, rr = (t % 20) / 5, o = t % 5;
    *(f16x8*)(Xs[bu] + (28 + rr)*40 + o*8) = z8;
  }
  if (t >= 64 && t < 128){ sg[t-64] = gg[t-64]; sb[t-64] = bb[t-64]; sw[t-64] = wsum[t-64]; }

  int mts[3], nts[3];
  #pragma unroll
  for (int s = 0; s < 3; s++){ const int mn = wid + s*4; mts[s] = mn >> 1; nts[s] = mn & 1; }
  f32x4 acc[3];
  #pragma unroll
  for (int s = 0; s < 3; s++) acc[s] = (f32x4){0.f,0.f,0.f,0.f};

  feat_stage4(x, pixbase, 0, Xs[0], t);
  __syncthreads();
  for (int kt = 0; kt < 20; kt++){
    if (kt < 19) feat_stage4(x, pixbase, kt+1, Xs[(kt+1)&1], t);
    const f16* xb = Xs[kt&1];
    #pragma unroll
    for (int s = 0; s < 3; s++){
      const int mn = wid + s*4;
      if (mn < 10){
        const f16x8 a8 = *(const f16x8*)(W65 + (size_t)(mts[s]*16 + r16)*640 + kt*32 + kbq*8);
        const f16x8 b8 = *(const f16x8*)(xb + (nts[s]*16 + r16)*40 + kbq*8);
        acc[s] = __builtin_amdgcn_mfma_f32_16x16x32_f16(a8, b8, acc[s], 0, 0, 0);
      }
    }
    __syncthreads();
  }
  #pragma unroll
  for (int s = 0; s < 3; s++){
    const int mn = wid + s*4;
    if (mn < 10){
      const int col = nts[s]*16 + r16, rb = mts[s]*16 + kbq*4;
      #pragma unroll
      for (int r = 0; r < 4; r++) Ys[col*85 + rb + r] = acc[s][r];
    }
  }
  __syncthreads();

  if (t < 224){
    const int pixl = t >> 3, oo = t & 7;
    const int pixg = pixbase + pixl;
    const bool ok = (pixg < 100);
    const float m = Ys[pixl*85 + 64] * (1.f/640.f);
    float yr[8]; float ssq = 0.f;
    #pragma unroll
    for (int j = 0; j < 8; j++){
      const int o = oo*8 + j;
      float yv = 0.f;
      if (ok) yv = fmaxf(sg[o]*(Ys[pixl*85 + o] - sw[o]*m) + sb[o], 0.f);
      yr[j] = yv; ssq += yv*yv;
    }
    ssq += __shfl_xor(ssq, 1); ssq += __shfl_xor(ssq, 2); ssq += __shfl_xor(ssq, 4);
    const float inv = ok ? (1.f / fmaxf(sqrtf(ssq), 1e-8f)) : 0.f;
    #pragma unroll
    for (int j2 = 0; j2 < 4; j2++){
      f16x2 hv = { (f16)(yr[2*j2]*inv), (f16)(yr[2*j2+1]*inv) };
      *(f16x2*)(out16 + (size_t)pixg*64 + oo*8 + 2*j2) = hv;
    }
    if (oo == 0 && ok) mout[pixg] = m;
  }
}

// ---------------- k_z: corr + layer0 as three MFMA GEMMs -> z (f16) ----------------
__global__ __launch_bounds__(256) void k_z(
    const f16* __restrict__ s16, const f16* __restrict__ q16,
    const float* __restrict__ cp, const f16* __restrict__ MuF, const f16* __restrict__ MhF,
    f16* __restrict__ z)
{
  __shared__ __align__(16) f16 smz[112*120 + 112*120 + 16];
  f16* cbT = smz;
  f16* tS  = smz + 112*120;
  const int pair = blockIdx.x;
  const int q = pair / WAYT, w = pair % WAYT;
  const int t = threadIdx.x, l = t & 63, wid = t >> 6;
  const int r16 = l & 15, kb = (l >> 4) & 3;

  {
    const f16x8 z8 = {(f16)0,(f16)0,(f16)0,(f16)0,(f16)0,(f16)0,(f16)0,(f16)0};
    if (t < 112){
      *(f16x8*)(cbT + t*120 + 112) = z8;
      *(f16x8*)(tS  + t*120 + 112) = z8;
    }
    if (t < 16) tS[112*120 + t] = (f16)0;
    if (t >= 240 && t < 248) tS[t - 240] = (f16)0;
  }

  const f16* sbase = s16 + (size_t)w * 7168;
  const f16* qbase = q16 + (size_t)q * 7168;

  for (int mn = wid; mn < 49; mn += 4){
    const int mt = mn / 7, nt = mn - (mn/7)*7;
    const f16x8 a0 = *(const f16x8*)(sbase + (mt*16 + r16)*64 + kb*8);
    const f16x8 a1 = *(const f16x8*)(sbase + (mt*16 + r16)*64 + 32 + kb*8);
    const f16x8 b0 = *(const f16x8*)(qbase + (nt*16 + r16)*64 + kb*8);
    const f16x8 b1 = *(const f16x8*)(qbase + (nt*16 + r16)*64 + 32 + kb*8);
    f32x4 acc = {0.f,0.f,0.f,0.f};
    acc = __builtin_amdgcn_mfma_f32_16x16x32_f16(a0, b0, acc, 0, 0, 0);
    acc = __builtin_amdgcn_mfma_f32_16x16x32_f16(a1, b1, acc, 0, 0, 0);
    union { f16x4 v4; f16x2 h2[2]; } hv;
    hv.h2[0] = pkrtz(acc[0], acc[1]);
    hv.h2[1] = pkrtz(acc[2], acc[3]);
    *(f16x4*)(cbT + (nt*16 + r16)*120 + mt*16 + kb*4) = hv.v4;
  }
  __syncthreads();

  const float g20 = cp[CP_SC+0], b20 = cp[CP_SC+1];
  for (int mn = wid; mn < 49; mn += 4){
    const int mt = mn / 7, nt = mn - (mn/7)*7;
    f32x4 acc = {0.f,0.f,0.f,0.f};
    #pragma unroll
    for (int kt = 0; kt < 4; kt++){
      const f16x8 a8 = *(const f16x8*)(cbT + (mt*16 + r16)*120 + kt*32 + kb*8);
      const f16x8 b8 = *(const f16x8*)(MuF + (size_t)(nt*4 + kt)*512 + l*8);
      acc = __builtin_amdgcn_mfma_f32_16x16x32_f16(a8, b8, acc, 0, 0, 0);
    }
    union { f16x4 v4; f16x2 h2[2]; } hv;
    hv.h2[0] = pkrtz(fmaxf(g20*acc[0] + b20, 0.f), fmaxf(g20*acc[1] + b20, 0.f));
    hv.h2[1] = pkrtz(fmaxf(g20*acc[2] + b20, 0.f), fmaxf(g20*acc[3] + b20, 0.f));
    *(f16x4*)(tS + (nt*16 + r16)*120 + mt*16 + kb*4) = hv.v4;
  }
  __syncthreads();

  const float g10 = cp[CP_SC+2], b10 = cp[CP_SC+3];
  for (int mn = wid; mn < 49; mn += 4){
    const int mt = mn / 7, nt = mn - (mn/7)*7;
    f32x4 acc = {0.f,0.f,0.f,0.f};
    #pragma unroll
    for (int kt = 0; kt < 4; kt++){
      const f16x8 a8 = *(const f16x8*)(tS + (mt*16 + r16)*120 + kt*32 + kb*8);
      const f16x8 b8 = *(const f16x8*)(MhF + (size_t)(nt*4 + kt)*512 + l*8);
      acc = __builtin_amdgcn_mfma_f32_16x16x32_f16(a8, b8, acc, 0, 0, 0);
    }
    const int hw = nt*16 + r16;
    if (hw < 100){
      #pragma unroll
      for (int r = 0; r < 4; r++){
        const int uv = mt*16 + kb*4 + r;
        if (uv < 100) z[(size_t)pair*10000 + uv*100 + hw] = (f16)(g10*acc[r] + b10);
      }
    }
  }
}

// ---------------- k_l1: 512 threads, 8 waves, taps 0-7 K32 + tap8 K16 ----------------
__global__ __launch_bounds__(512, 8) void k_l1(
    const f16* __restrict__ z, const float* __restrict__ cp,
    const f16* __restrict__ Apack, const f16* __restrict__ Wf2, const f16* __restrict__ Wf8,
    f16* __restrict__ F)
{
  __shared__ f16 z3[3*1216];
  __shared__ f16 Gs[9*GS_STRIDE];
  const int u = blockIdx.x, pair = blockIdx.y;
  const int t = threadIdx.x, l = t & 63, wid = t >> 6;
  const int r16 = l & 15, kb = (l >> 4) & 3;
  const int khi = kb & 1, half = kb >> 1;

  for (int e = t; e < 1824; e += 512){
    const int du = e / 608, c2 = e - du*608;
    const int ur = u + du - 1;
    const int colb = c2*2;
    const int g = colb - 100;
    f16x2 v = {(f16)0, (f16)0};
    if (ur >= 0 && ur <= 9 && g >= 0 && g < 1000)
      v = *(const f16x2*)(z + (size_t)pair*10000 + ur*1000 + g);
    *(f16x2*)(z3 + du*1216 + colb) = v;
  }

  f16x2 Ac2[4], Bc2[4];
  {
    const float4 a4a = ((const float4*)(cp + CP_A))[khi*2];
    const float4 a4b = ((const float4*)(cp + CP_A))[khi*2+1];
    const float4 b4a = ((const float4*)(cp + CP_B))[khi*2];
    const float4 b4b = ((const float4*)(cp + CP_B))[khi*2+1];
    Ac2[0] = (f16x2){(f16)a4a.x,(f16)a4a.y}; Ac2[1] = (f16x2){(f16)a4a.z,(f16)a4a.w};
    Ac2[2] = (f16x2){(f16)a4b.x,(f16)a4b.y}; Ac2[3] = (f16x2){(f16)a4b.z,(f16)a4b.w};
    Bc2[0] = (f16x2){(f16)b4a.x,(f16)b4a.y}; Bc2[1] = (f16x2){(f16)b4a.z,(f16)b4a.w};
    Bc2[2] = (f16x2){(f16)b4b.x,(f16)b4b.y}; Bc2[3] = (f16x2){(f16)b4b.z,(f16)b4b.w};
  }
  f16x2 Ac8[2], Bc8[2];
  {
    // tap-8 K16: lane K-slice = cin [kb*4, kb*4+4)
    const float4 a4 = ((const float4*)(cp + CP_A))[kb];
    const float4 b4 = ((const float4*)(cp + CP_B))[kb];
    Ac8[0] = (f16x2){(f16)a4.x,(f16)a4.y}; Ac8[1] = (f16x2){(f16)a4.z,(f16)a4.w};
    Bc8[0] = (f16x2){(f16)b4.x,(f16)b4.y}; Bc8[1] = (f16x2){(f16)b4.z,(f16)b4.w};
  }
  f16x8 af[4];
  #pragma unroll
  for (int p = 0; p < 4; p++) af[p] = ((const f16x8*)Apack)[p*64 + l];
  const f16x4 wf  = ((const f16x4*)Wf2)[l];
  const f16x4 wf8 = ((const f16x4*)Wf8)[l];

  float gv[4], bm[4], bv0[4], bv9[4];
  #pragma unroll
  for (int r = 0; r < 4; r++){
    const int co = kb*4 + r;
    gv[r] = cp[CP_G2 + co];
    const float b0 = cp[CP_B2 + co];
    float c0 = 0.f, cv0 = 0.f, cv9 = 0.f;
    #pragma unroll
    for (int du = 0; du < 3; du++){
      const int ur = u + du - 1;
      const float t0 = cp[CP_T9 + (du*3+0)*16 + co];
      const float t1 = cp[CP_T9 + (du*3+1)*16 + co];
      const float t2 = cp[CP_T9 + (du*3+2)*16 + co];
      if (ur < 0 || ur > 9) c0 += t0 + t1 + t2;
      else { cv0 += t0; cv9 += t2; }
    }
    bm[r]  = b0 - gv[r]*c0;
    bv0[r] = bm[r] - gv[r]*cv0;
    bv9[r] = bm[r] - gv[r]*cv9;
  }
  int zoffE[4];
  #pragma unroll
  for (int p = 0; p < 4; p++){
    const int tap = 2*p + half;           // taps 0..7
    const int du = tap/3, dv = tap%3;
    zoffE[p] = du*1216 + dv*100;
  }
  const int zoff8 = 2*1216 + 2*100;       // tap 8: du=2, dv=2
  __syncthreads();

  const f16x2 zero2 = {(f16)0, (f16)0};
  #pragma unroll 1
  for (int i = 0; i < 8; i++){
    const int cbase = (wid + i*8)*16;
    if (cbase >= 1008) break;            // wave-uniform
    const int c = cbase + r16;
    const int v = (c * 5243) >> 19;
    f32x4 acc = {0.f,0.f,0.f,0.f};
    #pragma unroll
    for (int p = 0; p < 4; p++){
      const f16 zv = z3[zoffE[p] + c];
      const f16x2 zz = {zv, zv};
      union { f16x8 v8; f16x2 h2[4]; } bu;
      #pragma unroll
      for (int j2 = 0; j2 < 4; j2++){
        f16x2 r2 = Ac2[j2] * zz + Bc2[j2];
        bu.h2[j2] = __builtin_elementwise_max(r2, zero2);
      }
      acc = __builtin_amdgcn_mfma_f32_16x16x32_f16(af[p], bu.v8, acc, 0, 0, 0);
    }
    {
      const f16 zv8 = z3[zoff8 + c];
      const f16x2 z8 = {zv8, zv8};
      union { f16x4 v4; f16x2 h2[2]; } b8u;
      b8u.h2[0] = __builtin_elementwise_max(Ac8[0]*z8 + Bc8[0], zero2);
      b8u.h2[1] = __builtin_elementwise_max(Ac8[1]*z8 + Bc8[1], zero2);
      acc = __builtin_amdgcn_mfma_f32_16x16x16f16(wf8, b8u.v4, acc, 0, 0, 0);
    }
    const bool isv0 = (v == 0), isv9 = (v == 9);
    float rr[4];
    #pragma unroll
    for (int r = 0; r < 4; r++){
      const float bsel = isv0 ? bv0[r] : (isv9 ? bv9[r] : bm[r]);
      rr[r] = fmaxf(fmaf(gv[r], acc[r], bsel), 0.f);
    }
    union { f16x4 v4; f16x2 h2[2]; } t1u;
    t1u.h2[0] = pkrtz(rr[0], rr[1]);
    t1u.h2[1] = pkrtz(rr[2], rr[3]);
    f32x4 g = {0.f,0.f,0.f,0.f};
    g = __builtin_amdgcn_mfma_f32_16x16x16f16(wf, t1u.v4, g, 0, 0, 0);
    #pragma unroll
    for (int r = 0; r < 4; r++){
      const int tap = kb*4 + r;
      if (tap <= 8) Gs[tap*GS_STRIDE + 16 + c] = (f16)g[r];
    }
  }
  __syncthreads();

  const float Kc = cp[CP_SC+4];
  #pragma unroll 1
  for (int oo = 0; oo < 2; oo++){
    const int c = t + oo*512;
    if (c < 1000){
      const int hw = c - ((c * 5243) >> 19) * 100;
      const int h = (hw * 205) >> 11, w2 = hw - h*10;
      float o = Kc;
      #pragma unroll
      for (int dh = 0; dh < 3; dh++){
        #pragma unroll
        for (int dw = 0; dw < 3; dw++){
          const bool okg = ((unsigned)(h + dh - 1) <= 9u) && ((unsigned)(w2 + dw - 1) <= 9u);
          const float gvv = (float)Gs[(dh*3+dw)*GS_STRIDE + 16 + c + (dh-1)*10 + (dw-1)];
          o += okg ? gvv : 0.f;
        }
      }
      F[(size_t)pair*10000 + u*1000 + c] = (f16)o;
    }
  }
}

// ---------------- attn_a: gnorm + softmax -> asq (f32) + asqh (f16), zero-padded ----------------
__global__ __launch_bounds__(256) void k_attn_a(const f16* __restrict__ F,
                                                float* __restrict__ asq, f16* __restrict__ asqh)
{
  __shared__ float fb[100*101 + 4];
  __shared__ float isc[100], ccs[100], isr[100], ccr[100];
  const int pair = blockIdx.x;
  const int t = threadIdx.x;
  const float L2T = 1.4426950408889634f * 0.2f;

  for (int e = t; e < 10000; e += 256)
    fb[(e/100)*101 + (e%100)] = (float)F[(size_t)pair*10000 + e];
  __syncthreads();

  {
    const int line = t & 127;
    const bool isCol = t < 128;
    if (line < 100){
      const int base = isCol ? line : line*101;
      const int stride = isCol ? 101 : 1;
      float s = 0.f, ss = 0.f;
      for (int i = 0; i < 100; i++){ const float x = fb[base + i*stride]; s += x; ss += x*x; }
      const float m = s * 0.01f;
      const float var = (ss - 100.f*m*m) * (1.f/99.f);
      const float is2 = rsqrtf(var + 1e-5f) * L2T;
      float S = 0.f;
      for (int i = 0; i < 100; i++) S += exp2f((fb[base + i*stride] - m) * is2);
      const float cc = m*is2 + log2f(S);
      if (isCol){ isc[line] = is2; ccs[line] = cc; }
      else      { isr[line] = is2; ccr[line] = cc; }
    }
  }
  __syncthreads();
  {
    const int line = t & 127;
    if (line < 100){
      if (t < 128){
        float a = 0.f;
        for (int k = 0; k < 100; k++)
          a += exp2f(fb[line*101 + k] * isc[k] - ccs[k]);
        asq[(size_t)pair*256 + line] = a;
        asqh[(size_t)pair*256 + line] = (f16)a;
      } else {
        float a = 0.f;
        for (int k = 0; k < 100; k++)
          a += exp2f(fb[k*101 + line] * isr[k] - ccr[k]);
        asq[(size_t)pair*256 + 128 + line] = a;
        asqh[(size_t)pair*256 + 128 + line] = (f16)a;
      }
    } else {
      asq[(size_t)pair*256 + t] = 0.f;
      asqh[(size_t)pair*256 + t] = (f16)0;
    }
  }
}

// ---------------- spqp: 350 blocks; all-f16 fragment loads on sp path ----------------
__global__ __launch_bounds__(256) void k_spqp(
    const f16* __restrict__ spt16, const float* __restrict__ qry,
    const f16* __restrict__ asqh, float* __restrict__ P)
{
  const int b = blockIdx.x;
  const int t = threadIdx.x, l = t & 63, wid = t >> 6;
  const int r16 = l & 15, kb = (l >> 4) & 3;

  if (b < 50){
    const int w = b / 10, c0 = (b % 10) * 64;
    const int c = c0 + wid*16 + r16;
    f16x8 bf[4];
    #pragma unroll
    for (int kt = 0; kt < 4; kt++)
      bf[kt] = *(const f16x8*)(spt16 + ((size_t)w*640 + c)*128 + kt*32 + kb*8);
    #pragma unroll 1
    for (int mt = 0; mt < 10; mt++){
      const int qr = mt*16 + r16;   // rows >=150 read garbage (allocated); outputs guarded
      f32x4 acc = {0.f,0.f,0.f,0.f};
      #pragma unroll
      for (int kt = 0; kt < 4; kt++){
        const f16x8 au = *(const f16x8*)(asqh + (size_t)(qr*5 + w)*256 + kt*32 + kb*8);
        acc = __builtin_amdgcn_mfma_f32_16x16x32_f16(au, bf[kt], acc, 0, 0, 0);
      }
      #pragma unroll
      for (int r = 0; r < 4; r++){
        const int q2 = mt*16 + kb*4 + r;
        if (q2 < 150) P[(size_t)(q2*5 + w)*1280 + c0 + wid*16 + (l & 15)] = acc[r];
      }
    }
  } else {
    const int idx = b - 50, q = idx >> 1, chalf = idx & 1;
    f16x8 af4[4];
    #pragma unroll
    for (int kt = 0; kt < 4; kt++)
      af4[kt] = *(const f16x8*)(asqh + (size_t)(q*5 + r16)*256 + 128 + kt*32 + kb*8);
    #pragma unroll 1
    for (int nt = chalf*20 + wid; nt < chalf*20 + 20; nt += 4){
      const int c = nt*16 + r16;
      f32x4 acc = {0.f,0.f,0.f,0.f};
      #pragma unroll
      for (int kt = 0; kt < 4; kt++){
        const int kbase = kt*32 + kb*8;
        float v[8];
        #pragma unroll
        for (int j = 0; j < 8; j++){
          const int k = kbase + j;
          v[j] = (k < 100) ? qry[(size_t)q*64000 + (size_t)c*100 + k] : 0.f;
        }
        union { f16x8 v8; f16x2 h2[4]; } uu;
        #pragma unroll
        for (int j2 = 0; j2 < 4; j2++) uu.h2[j2] = pkrtz(v[2*j2], v[2*j2+1]);
        acc = __builtin_amdgcn_mfma_f32_16x16x32_f16(af4[kt], uu.v8, acc, 0, 0, 0);
      }
      #pragma unroll
      for (int r = 0; r < 4; r++){
        const int w2 = kb*4 + r;
        if (w2 < 5) P[(size_t)(q*5 + w2)*1280 + 640 + nt*16 + (l & 15)] = acc[r];
      }
    }
  }
}

// ---------------- cos: mean-correct + cosine per pair ----------------
__global__ __launch_bounds__(256) void k_cos(
    const float* __restrict__ P, const float* __restrict__ asq,
    const float* __restrict__ sptm, const float* __restrict__ qrym,
    float* __restrict__ out)
{
  __shared__ float pred[4];
  __shared__ float MsMq[2];
  __shared__ float red[12];
  const int pair = blockIdx.x;
  const int q = pair / WAYT, w = pair % WAYT;
  const int t = threadIdx.x, wid = t >> 6;

  float pm = 0.f;
  if (t < 100) pm = asq[(size_t)pair*256 + t] * sptm[w*100 + t];
  else if (t >= 128 && t < 228) pm = asq[(size_t)pair*256 + t] * qrym[q*100 + (t - 128)];
  #pragma unroll
  for (int m = 1; m < 64; m <<= 1) pm += __shfl_xor(pm, m);
  if ((t & 63) == 0) pred[wid] = pm;
  __syncthreads();
  if (t == 0) MsMq[0] = pred[0] + pred[1];
  if (t == 1) MsMq[1] = pred[2] + pred[3];
  __syncthreads();
  const float Ms = MsMq[0], Mq = MsMq[1];

  float d0 = 0.f, d1 = 0.f, d2 = 0.f;
  for (int c = t; c < 640; c += 256){
    const float sp = P[(size_t)pair*1280 + c] - Ms;
    const float qp = P[(size_t)pair*1280 + 640 + c] - Mq;
    d0 += sp*qp; d1 += sp*sp; d2 += qp*qp;
  }
  #pragma unroll
  for (int m = 1; m < 64; m <<= 1){
    d0 += __shfl_xor(d0, m); d1 += __shfl_xor(d1, m); d2 += __shfl_xor(d2, m);
  }
  if ((t & 63) == 0){ red[wid*3+0] = d0; red[wid*3+1] = d1; red[wid*3+2] = d2; }
  __syncthreads();
  if (t == 0){
    float e0 = 0.f, e1 = 0.f, e2 = 0.f;
    #pragma unroll
    for (int k = 0; k < 4; k++){ e0 += red[k*3]; e1 += red[k*3+1]; e2 += red[k*3+2]; }
    const float den = fmaxf(sqrtf(e1), 1e-8f) * fmaxf(sqrtf(e2), 1e-8f);
    out[pair] = (e0 / den) * 5.0f;
  }
}

extern "C" void kernel_launch(void* const* d_in, const int* in_sizes, int n_in,
                              void* d_out, int out_size, void* d_ws, size_t ws_size,
                              hipStream_t stream)
{
  (void)in_sizes; (void)n_in; (void)out_size; (void)ws_size;
  const float* spt = (const float*)d_in[0];
  const float* qry = (const float*)d_in[1];
  const float* Wc  = (const float*)d_in[2];
  const float* gc  = (const float*)d_in[3];
  const float* bc  = (const float*)d_in[4];

  float* ws    = (float*)d_ws;
  float* cp    = ws;                          // 256
  float* wsum  = ws + 256;                    // 64
  float* sptm  = ws + 320;                    // 500
  float* qrym  = ws + 820;                    // 15000 -> pad 15872
  f16*  Apack  = (f16*)(ws + 15872);          // 2560 f16
  f16*  Wf2    = (f16*)(ws + 17152);          // 256 f16
  f16*  Wf8    = (f16*)(ws + 17280);          // 256 f16
  f16*  W65    = (f16*)(ws + 17408);          // 51200 f16
  f16*  MuF    = (f16*)(ws + 43008);          // 14336 f16
  f16*  MhF    = (f16*)(ws + 50176);          // 14336 f16
  f16*  s16    = (f16*)(ws + 57344);          // 35840 f16
  f16*  q16    = (f16*)(ws + 75264);          // 1075200 f16
  f16*  z      = (f16*)(ws + 612864);         // 7.5M f16
  f16*  F      = (f16*)(ws + 4362864);        // 7.5M f16
  f16*  spt16  = (f16*)(ws + 8112864);        // 409600 f16 (end ~33.3 MB)
  // aliases (lifetime-disjoint):
  float* asq   = ws + 75264;                  // over q16 (dead after k_z); 192000 f32
  f16*  asqh   = (f16*)(ws + 75264 + 192000); // over q16; 800x256 f16 (rows >=750 unwritten, reads guarded by output masks)
  float* P     = ws + 612864;                 // over z (dead after k_l1); 960000 f32

  k_prep_all<<<241, 256, 0, stream>>>(
      spt, Wc,
      (const float*)d_in[5],  (const float*)d_in[6],  (const float*)d_in[7],
      (const float*)d_in[8],  (const float*)d_in[9],  (const float*)d_in[10],
      (const float*)d_in[11], (const float*)d_in[12], (const float*)d_in[13],
      (const float*)d_in[14], (const float*)d_in[15], (const float*)d_in[16],
      (const float*)d_in[17], (const float*)d_in[18], (const float*)d_in[19],
      (const float*)d_in[20], (const float*)d_in[21], (const float*)d_in[22],
      cp, Apack, Wf2, Wf8, MuF, MhF, W65, wsum, spt16);
  k_feat<<<620, 256, 0, stream>>>(spt, qry, W65, wsum, gc, bc, s16, q16, sptm, qrym);
  k_z<<<NQT*WAYT, 256, 0, stream>>>(s16, q16, cp, MuF, MhF, z);
  {
    dim3 grid(10, NQT*WAYT);
    k_l1<<<grid, 512, 0, stream>>>(z, cp, Apack, Wf2, Wf8, F);
  }
  k_attn_a<<<NQT*WAYT, 256, 0, stream>>>(F, asq, asqh);
  k_spqp<<<350, 256, 0, stream>>>(spt16, qry, asqh, P);
  k_cos<<<NQT*WAYT, 256, 0, stream>>>(P, asq, sptm, qrym, (float*)d_out);
}

// Round 11
// 226.837 us; speedup vs baseline: 1.3904x; 1.3904x over previous
//
#include <hip/hip_runtime.h>
#include <cstdint>
#include <cstddef>

#define NQT   150
#define WAYT  5
#define CCH   640

typedef _Float16 f16;
typedef _Float16 f16x2 __attribute__((ext_vector_type(2)));
typedef _Float16 f16x4 __attribute__((ext_vector_type(4)));
typedef _Float16 f16x8 __attribute__((ext_vector_type(8)));
typedef float    f32x4 __attribute__((ext_vector_type(4)));

static __device__ __forceinline__ f16x2 pkrtz(float a, float b){
  return __builtin_bit_cast(f16x2, __builtin_amdgcn_cvt_pkrtz(a, b));
}

// const-pack offsets (floats)
#define CP_A     0
#define CP_B     16
#define CP_G2    32
#define CP_B2    48
#define CP_W20   64
#define CP_W10   73
#define CP_SC    82
#define CP_T9    96
#define GS_STRIDE 1076

// stencil matrix value: Mat[k = src pos][n = dst pos], 10x10 grid, 3x3 taps
static __device__ __forceinline__ float stencil9(int k, int n, const float* __restrict__ w9){
  if (k >= 100 || n >= 100) return 0.f;
  const int a = n/10, b = n%10, a2 = k/10, b2 = k%10;
  const int dA = a2 - a + 1, dB = b2 - b + 1;
  if ((unsigned)dA > 2u || (unsigned)dB > 2u) return 0.f;
  return w9[dA*3 + dB];
}

// ---------------- prep (merged; grid 241) ----------------
__global__ __launch_bounds__(256) void k_prep_all(
    const float* __restrict__ spt, const float* __restrict__ W,
    const float* __restrict__ s0_w2, const float* __restrict__ s0_g2, const float* __restrict__ s0_b2,
    const float* __restrict__ s0_w1, const float* __restrict__ s0_g1, const float* __restrict__ s0_b1,
    const float* __restrict__ s0_wp, const float* __restrict__ s0_gp, const float* __restrict__ s0_bp,
    const float* __restrict__ s1_w2, const float* __restrict__ s1_g2, const float* __restrict__ s1_b2,
    const float* __restrict__ s1_w1, const float* __restrict__ s1_g1, const float* __restrict__ s1_b1,
    const float* __restrict__ s1_wp, const float* __restrict__ s1_gp, const float* __restrict__ s1_bp,
    float* __restrict__ cp, f16* __restrict__ Apack, f16* __restrict__ Wf2,
    f16* __restrict__ MuF, f16* __restrict__ MhF,
    f16* __restrict__ W65, float* __restrict__ wsum, f16* __restrict__ spt16)
{
  const int b = blockIdx.x, t = threadIdx.x;
  if (b == 0){
    for (int e = t; e < 2560; e += 256){
      int p = e / 512, r = e % 512, l = r / 8, j = r % 8;
      int kb = l >> 4;
      int tap = 2*p + (kb >> 1);
      int cin = (kb & 1)*8 + j;
      int co = l & 15;
      float v = 0.f;
      if (tap <= 8){
        int du = tap / 3, dv = tap % 3;
        v = s1_w2[((co*16 + cin)*3 + du)*3 + dv];
      }
      Apack[e] = (f16)v;
    }
    const float gp1 = s1_gp[0];
    {
      int l = t >> 2, j = t & 3;
      int tap = l & 15, ci = ((l >> 4) << 2) + j;
      float v = 0.f;
      if (tap <= 8){
        for (int co = 0; co < 16; co++)
          v += gp1 * s1_wp[co] * s1_g1[co] * s1_w1[(co*16 + ci)*9 + tap];
      }
      Wf2[t] = (f16)v;
    }
    if (t < 144){
      int tap = t / 16, co = t % 16;
      float s = 0.f;
      for (int cin = 0; cin < 16; cin++){
        float wv = (float)(f16)s1_w2[((co*16 + cin)*3 + tap/3)*3 + tap%3];
        float rb = fmaxf((float)(f16)s0_bp[cin], 0.f);
        s += wv * rb;
      }
      cp[CP_T9 + t] = s;
    }
    if (t < 16){
      cp[CP_A + t]  = s0_gp[t] * s0_wp[t];
      cp[CP_B + t]  = s0_bp[t];
      cp[CP_G2 + t] = s1_g2[t];
      cp[CP_B2 + t] = s1_b2[t];
    }
    if (t < 9){ cp[CP_W20 + t] = s0_w2[t]; cp[CP_W10 + t] = s0_w1[t]; }
    if (t == 0){
      cp[CP_SC + 0] = s0_g2[0]; cp[CP_SC + 1] = s0_b2[0];
      cp[CP_SC + 2] = s0_g1[0]; cp[CP_SC + 3] = s0_b1[0];
      float kk = 0.f;
      for (int co = 0; co < 16; co++) kk += s1_wp[co] * s1_b1[co];
      cp[CP_SC + 4] = gp1 * kk + s1_bp[0];
    }
  } else if (b <= 14){
    const bool isMu = (b <= 7);
    f16* dst = isMu ? MuF : MhF;
    const float* w9 = isMu ? s0_w2 : s0_w1;
    const int base = (isMu ? (b-1) : (b-8)) * 2048;
    #pragma unroll
    for (int e2 = 0; e2 < 8; e2++){
      const int idx = base + e2*256 + t;
      const int j = idx & 7, l2 = (idx >> 3) & 63, ktnt = idx >> 9;
      const int kt = ktnt & 3, nt = ktnt >> 2;
      const int n = nt*16 + (l2 & 15);
      const int k = kt*32 + ((l2 >> 4) & 3)*8 + j;
      dst[idx] = (f16)stencil9(k, n, w9);
    }
  } else if (b <= 39){
    const int base = (b - 15) * 2048;
    #pragma unroll
    for (int e2 = 0; e2 < 8; e2++){
      const int idx = base + e2*256 + t;
      const int row = idx / 640, c = idx - row*640;
      float v = 0.f;
      if (row < 64) v = W[row*640 + c];
      else if (row == 64) v = 1.f;
      W65[idx] = (f16)v;
    }
  } else if (b == 40){
    const int o = t >> 2, qq = t & 3;
    float s = 0.f;
    for (int c = qq; c < 640; c += 4) s += W[o*640 + c];
    s += __shfl_xor(s, 1); s += __shfl_xor(s, 2);
    if (qq == 0) wsum[o] = s;
  } else {
    // spt16: [5][640][128] f16, k>=100 zero
    const int base = (b - 41) * 2048;
    #pragma unroll
    for (int e2 = 0; e2 < 8; e2++){
      const int idx = base + e2*256 + t;
      const int w = idx / 81920, r = idx % 81920;
      const int c = r >> 7, k = r & 127;
      spt16[idx] = (k < 100) ? (f16)spt[(size_t)w*64000 + c*100 + k] : (f16)0;
    }
  }
}

// ---------------- feat: 620 blocks; GEMM Y[80][32] per block ----------------
__device__ __forceinline__ void feat_stage4(const float* __restrict__ x, int pixoff, int kt,
                                            f16* __restrict__ dst, int t){
  if (t < 224){
    const int cc = t / 7, qd = t % 7;
    float4 v4 = make_float4(0.f, 0.f, 0.f, 0.f);
    if (pixoff + qd*4 + 4 <= 100)
      v4 = *(const float4*)(x + (size_t)(kt*32 + cc)*100 + pixoff + qd*4);
    dst[(qd*4+0)*40 + cc] = (f16)v4.x;
    dst[(qd*4+1)*40 + cc] = (f16)v4.y;
    dst[(qd*4+2)*40 + cc] = (f16)v4.z;
    dst[(qd*4+3)*40 + cc] = (f16)v4.w;
  }
}

__global__ __launch_bounds__(256) void k_feat(
    const float* __restrict__ spt, const float* __restrict__ qry,
    const f16* __restrict__ W65, const float* __restrict__ wsum,
    const float* __restrict__ gg, const float* __restrict__ bb,
    f16* __restrict__ s16, f16* __restrict__ q16,
    float* __restrict__ sptm, float* __restrict__ qrym)
{
  __shared__ f16 Xs[2][32*40];
  __shared__ float Ys[32*85];
  __shared__ float sg[64], sb[64], sw[64];
  const int b = blockIdx.x;
  const int n = b >> 2, quarter = b & 3;
  const int pixbase = quarter * 28;
  const float* x; f16* out16; float* mout;
  if (n < 5){ x = spt + (size_t)n*64000; out16 = s16 + (size_t)n*7168; mout = sptm + n*100; }
  else { x = qry + (size_t)(n-5)*64000; out16 = q16 + (size_t)(n-5)*7168; mout = qrym + (size_t)(n-5)*100; }
  const int t = threadIdx.x, l = t & 63, wid = t >> 6;
  const int r16 = l & 15, kbq = (l >> 4) & 3;

  if (t < 40){
    const f16x8 z8 = {(f16)0,(f16)0,(f16)0,(f16)0,(f16)0,(f16)0,(f16)0,(f16)0};
    const int bu = t / 20, rr = (t % 20) / 5, o = t % 5;
    *(f16x8*)(Xs[bu] + (28 + rr)*40 + o*8) = z8;
  }
  if (t >= 64 && t < 128){ sg[t-64] = gg[t-64]; sb[t-64] = bb[t-64]; sw[t-64] = wsum[t-64]; }

  int mts[3], nts[3];
  #pragma unroll
  for (int s = 0; s < 3; s++){ const int mn = wid + s*4; mts[s] = mn >> 1; nts[s] = mn & 1; }
  f32x4 acc[3];
  #pragma unroll
  for (int s = 0; s < 3; s++) acc[s] = (f32x4){0.f,0.f,0.f,0.f};

  feat_stage4(x, pixbase, 0, Xs[0], t);
  __syncthreads();
  for (int kt = 0; kt < 20; kt++){
    if (kt < 19) feat_stage4(x, pixbase, kt+1, Xs[(kt+1)&1], t);
    const f16* xb = Xs[kt&1];
    #pragma unroll
    for (int s = 0; s < 3; s++){
      const int mn = wid + s*4;
      if (mn < 10){
        const f16x8 a8 = *(const f16x8*)(W65 + (size_t)(mts[s]*16 + r16)*640 + kt*32 + kbq*8);
        const f16x8 b8 = *(const f16x8*)(xb + (nts[s]*16 + r16)*40 + kbq*8);
        acc[s] = __builtin_amdgcn_mfma_f32_16x16x32_f16(a8, b8, acc[s], 0, 0, 0);
      }
    }
    __syncthreads();
  }
  #pragma unroll
  for (int s = 0; s < 3; s++){
    const int mn = wid + s*4;
    if (mn < 10){
      const int col = nts[s]*16 + r16, rb = mts[s]*16 + kbq*4;
      #pragma unroll
      for (int r = 0; r < 4; r++) Ys[col*85 + rb + r] = acc[s][r];
    }
  }
  __syncthreads();

  if (t < 224){
    const int pixl = t >> 3, oo = t & 7;
    const int pixg = pixbase + pixl;
    const bool ok = (pixg < 100);
    const float m = Ys[pixl*85 + 64] * (1.f/640.f);
    float yr[8]; float ssq = 0.f;
    #pragma unroll
    for (int j = 0; j < 8; j++){
      const int o = oo*8 + j;
      float yv = 0.f;
      if (ok) yv = fmaxf(sg[o]*(Ys[pixl*85 + o] - sw[o]*m) + sb[o], 0.f);
      yr[j] = yv; ssq += yv*yv;
    }
    ssq += __shfl_xor(ssq, 1); ssq += __shfl_xor(ssq, 2); ssq += __shfl_xor(ssq, 4);
    const float inv = ok ? (1.f / fmaxf(sqrtf(ssq), 1e-8f)) : 0.f;
    #pragma unroll
    for (int j2 = 0; j2 < 4; j2++){
      f16x2 hv = { (f16)(yr[2*j2]*inv), (f16)(yr[2*j2+1]*inv) };
      *(f16x2*)(out16 + (size_t)pixg*64 + oo*8 + 2*j2) = hv;
    }
    if (oo == 0 && ok) mout[pixg] = m;
  }
}

// ---------------- k_z: corr + layer0 as three MFMA GEMMs -> z (f16) ----------------
__global__ __launch_bounds__(256) void k_z(
    const f16* __restrict__ s16, const f16* __restrict__ q16,
    const float* __restrict__ cp, const f16* __restrict__ MuF, const f16* __restrict__ MhF,
    f16* __restrict__ z)
{
  __shared__ __align__(16) f16 smz[112*120 + 112*120 + 16];
  f16* cbT = smz;
  f16* tS  = smz + 112*120;
  const int pair = blockIdx.x;
  const int q = pair / WAYT, w = pair % WAYT;
  const int t = threadIdx.x, l = t & 63, wid = t >> 6;
  const int r16 = l & 15, kb = (l >> 4) & 3;

  {
    const f16x8 z8 = {(f16)0,(f16)0,(f16)0,(f16)0,(f16)0,(f16)0,(f16)0,(f16)0};
    if (t < 112){
      *(f16x8*)(cbT + t*120 + 112) = z8;
      *(f16x8*)(tS  + t*120 + 112) = z8;
    }
    if (t < 16) tS[112*120 + t] = (f16)0;
    if (t >= 240 && t < 248) tS[t - 240] = (f16)0;
  }

  const f16* sbase = s16 + (size_t)w * 7168;
  const f16* qbase = q16 + (size_t)q * 7168;

  for (int mn = wid; mn < 49; mn += 4){
    const int mt = mn / 7, nt = mn - (mn/7)*7;
    const f16x8 a0 = *(const f16x8*)(sbase + (mt*16 + r16)*64 + kb*8);
    const f16x8 a1 = *(const f16x8*)(sbase + (mt*16 + r16)*64 + 32 + kb*8);
    const f16x8 b0 = *(const f16x8*)(qbase + (nt*16 + r16)*64 + kb*8);
    const f16x8 b1 = *(const f16x8*)(qbase + (nt*16 + r16)*64 + 32 + kb*8);
    f32x4 acc = {0.f,0.f,0.f,0.f};
    acc = __builtin_amdgcn_mfma_f32_16x16x32_f16(a0, b0, acc, 0, 0, 0);
    acc = __builtin_amdgcn_mfma_f32_16x16x32_f16(a1, b1, acc, 0, 0, 0);
    union { f16x4 v4; f16x2 h2[2]; } hv;
    hv.h2[0] = pkrtz(acc[0], acc[1]);
    hv.h2[1] = pkrtz(acc[2], acc[3]);
    *(f16x4*)(cbT + (nt*16 + r16)*120 + mt*16 + kb*4) = hv.v4;
  }
  __syncthreads();

  const float g20 = cp[CP_SC+0], b20 = cp[CP_SC+1];
  for (int mn = wid; mn < 49; mn += 4){
    const int mt = mn / 7, nt = mn - (mn/7)*7;
    f32x4 acc = {0.f,0.f,0.f,0.f};
    #pragma unroll
    for (int kt = 0; kt < 4; kt++){
      const f16x8 a8 = *(const f16x8*)(cbT + (mt*16 + r16)*120 + kt*32 + kb*8);
      const f16x8 b8 = *(const f16x8*)(MuF + (size_t)(nt*4 + kt)*512 + l*8);
      acc = __builtin_amdgcn_mfma_f32_16x16x32_f16(a8, b8, acc, 0, 0, 0);
    }
    union { f16x4 v4; f16x2 h2[2]; } hv;
    hv.h2[0] = pkrtz(fmaxf(g20*acc[0] + b20, 0.f), fmaxf(g20*acc[1] + b20, 0.f));
    hv.h2[1] = pkrtz(fmaxf(g20*acc[2] + b20, 0.f), fmaxf(g20*acc[3] + b20, 0.f));
    *(f16x4*)(tS + (nt*16 + r16)*120 + mt*16 + kb*4) = hv.v4;
  }
  __syncthreads();

  const float g10 = cp[CP_SC+2], b10 = cp[CP_SC+3];
  for (int mn = wid; mn < 49; mn += 4){
    const int mt = mn / 7, nt = mn - (mn/7)*7;
    f32x4 acc = {0.f,0.f,0.f,0.f};
    #pragma unroll
    for (int kt = 0; kt < 4; kt++){
      const f16x8 a8 = *(const f16x8*)(tS + (mt*16 + r16)*120 + kt*32 + kb*8);
      const f16x8 b8 = *(const f16x8*)(MhF + (size_t)(nt*4 + kt)*512 + l*8);
      acc = __builtin_amdgcn_mfma_f32_16x16x32_f16(a8, b8, acc, 0, 0, 0);
    }
    const int hw = nt*16 + r16;
    if (hw < 100){
      #pragma unroll
      for (int r = 0; r < 4; r++){
        const int uv = mt*16 + kb*4 + r;
        if (uv < 100) z[(size_t)pair*10000 + uv*100 + hw] = (f16)(g10*acc[r] + b10);
      }
    }
  }
}

// ---------------- k_l1: EXACT round-8 version (256 thr, (256,6), 5 paired-tap K32) ----------------
__global__ __launch_bounds__(256, 6) void k_l1(
    const f16* __restrict__ z, const float* __restrict__ cp,
    const f16* __restrict__ Apack, const f16* __restrict__ Wf2, f16* __restrict__ F)
{
  __shared__ f16 z3[3*1216];
  __shared__ f16 Gs[9*GS_STRIDE];
  const int u = blockIdx.x, pair = blockIdx.y;
  const int t = threadIdx.x, l = t & 63, wid = t >> 6;
  const int r16 = l & 15, kb = (l >> 4) & 3;
  const int khi = kb & 1, half = kb >> 1;

  for (int e = t; e < 1824; e += 256){
    const int du = e / 608, c2 = e - du*608;
    const int ur = u + du - 1;
    const int colb = c2*2;
    const int g = colb - 100;
    f16x2 v = {(f16)0, (f16)0};
    if (ur >= 0 && ur <= 9 && g >= 0 && g < 1000)
      v = *(const f16x2*)(z + (size_t)pair*10000 + ur*1000 + g);
    *(f16x2*)(z3 + du*1216 + colb) = v;
  }

  f16x2 Ac2[4], Bc2[4];
  {
    const float4 a4a = ((const float4*)(cp + CP_A))[khi*2];
    const float4 a4b = ((const float4*)(cp + CP_A))[khi*2+1];
    const float4 b4a = ((const float4*)(cp + CP_B))[khi*2];
    const float4 b4b = ((const float4*)(cp + CP_B))[khi*2+1];
    Ac2[0] = (f16x2){(f16)a4a.x,(f16)a4a.y}; Ac2[1] = (f16x2){(f16)a4a.z,(f16)a4a.w};
    Ac2[2] = (f16x2){(f16)a4b.x,(f16)a4b.y}; Ac2[3] = (f16x2){(f16)a4b.z,(f16)a4b.w};
    Bc2[0] = (f16x2){(f16)b4a.x,(f16)b4a.y}; Bc2[1] = (f16x2){(f16)b4a.z,(f16)b4a.w};
    Bc2[2] = (f16x2){(f16)b4b.x,(f16)b4b.y}; Bc2[3] = (f16x2){(f16)b4b.z,(f16)b4b.w};
  }
  f16x8 af[5];
  #pragma unroll
  for (int p = 0; p < 5; p++) af[p] = ((const f16x8*)Apack)[p*64 + l];
  const f16x4 wf = ((const f16x4*)Wf2)[l];

  float gv[4], bm[4], bv0[4], bv9[4];
  #pragma unroll
  for (int r = 0; r < 4; r++){
    const int co = kb*4 + r;
    gv[r] = cp[CP_G2 + co];
    const float b0 = cp[CP_B2 + co];
    float c0 = 0.f, cv0 = 0.f, cv9 = 0.f;
    #pragma unroll
    for (int du = 0; du < 3; du++){
      const int ur = u + du - 1;
      const float t0 = cp[CP_T9 + (du*3+0)*16 + co];
      const float t1 = cp[CP_T9 + (du*3+1)*16 + co];
      const float t2 = cp[CP_T9 + (du*3+2)*16 + co];
      if (ur < 0 || ur > 9) c0 += t0 + t1 + t2;
      else { cv0 += t0; cv9 += t2; }
    }
    bm[r]  = b0 - gv[r]*c0;
    bv0[r] = bm[r] - gv[r]*cv0;
    bv9[r] = bm[r] - gv[r]*cv9;
  }
  int zoffE[5];
  #pragma unroll
  for (int p = 0; p < 5; p++){
    const int tap = 2*p + half;
    const int du = (tap <= 8) ? tap/3 : 0;
    const int dv = (tap <= 8) ? tap%3 : 0;
    zoffE[p] = du*1216 + dv*100;
  }
  __syncthreads();

  const f16x2 zero2 = {(f16)0, (f16)0};
  #pragma unroll 1
  for (int i = 0; i < 16; i++){
    const int cbase = wid*256 + i*16;
    if (cbase >= 1008) break;
    const int c = cbase + r16;
    const int v = (c * 5243) >> 19;
    f32x4 acc = {0.f,0.f,0.f,0.f};
    #pragma unroll
    for (int p = 0; p < 5; p++){
      const f16 zv = z3[zoffE[p] + c];
      const f16x2 zz = {zv, zv};
      union { f16x8 v8; f16x2 h2[4]; } bu;
      #pragma unroll
      for (int j2 = 0; j2 < 4; j2++){
        f16x2 r2 = Ac2[j2] * zz + Bc2[j2];
        bu.h2[j2] = __builtin_elementwise_max(r2, zero2);
      }
      acc = __builtin_amdgcn_mfma_f32_16x16x32_f16(af[p], bu.v8, acc, 0, 0, 0);
    }
    const bool isv0 = (v == 0), isv9 = (v == 9);
    float rr[4];
    #pragma unroll
    for (int r = 0; r < 4; r++){
      const float bsel = isv0 ? bv0[r] : (isv9 ? bv9[r] : bm[r]);
      rr[r] = fmaxf(fmaf(gv[r], acc[r], bsel), 0.f);
    }
    union { f16x4 v4; f16x2 h2[2]; } t1u;
    t1u.h2[0] = pkrtz(rr[0], rr[1]);
    t1u.h2[1] = pkrtz(rr[2], rr[3]);
    f32x4 g = {0.f,0.f,0.f,0.f};
    g = __builtin_amdgcn_mfma_f32_16x16x16f16(wf, t1u.v4, g, 0, 0, 0);
    #pragma unroll
    for (int r = 0; r < 4; r++){
      const int tap = kb*4 + r;
      if (tap <= 8) Gs[tap*GS_STRIDE + 16 + c] = (f16)g[r];
    }
  }
  __syncthreads();

  const float Kc = cp[CP_SC+4];
  #pragma unroll 1
  for (int oo = 0; oo < 4; oo++){
    const int c = t + oo*256;
    if (c < 1000){
      const int hw = c - ((c * 5243) >> 19) * 100;
      const int h = (hw * 205) >> 11, w2 = hw - h*10;
      float o = Kc;
      #pragma unroll
      for (int dh = 0; dh < 3; dh++){
        #pragma unroll
        for (int dw = 0; dw < 3; dw++){
          const bool okg = ((unsigned)(h + dh - 1) <= 9u) && ((unsigned)(w2 + dw - 1) <= 9u);
          const float gvv = (float)Gs[(dh*3+dw)*GS_STRIDE + 16 + c + (dh-1)*10 + (dw-1)];
          o += okg ? gvv : 0.f;
        }
      }
      F[(size_t)pair*10000 + u*1000 + c] = (f16)o;
    }
  }
}

// ---------------- attn_a: gnorm + softmax -> asq (f32) + asqh (f16), zero-padded ----------------
__global__ __launch_bounds__(256) void k_attn_a(const f16* __restrict__ F,
                                                float* __restrict__ asq, f16* __restrict__ asqh)
{
  __shared__ float fb[100*101 + 4];
  __shared__ float isc[100], ccs[100], isr[100], ccr[100];
  const int pair = blockIdx.x;
  const int t = threadIdx.x;
  const float L2T = 1.4426950408889634f * 0.2f;

  for (int e = t; e < 10000; e += 256)
    fb[(e/100)*101 + (e%100)] = (float)F[(size_t)pair*10000 + e];
  __syncthreads();

  {
    const int line = t & 127;
    const bool isCol = t < 128;
    if (line < 100){
      const int base = isCol ? line : line*101;
      const int stride = isCol ? 101 : 1;
      float s = 0.f, ss = 0.f;
      for (int i = 0; i < 100; i++){ const float x = fb[base + i*stride]; s += x; ss += x*x; }
      const float m = s * 0.01f;
      const float var = (ss - 100.f*m*m) * (1.f/99.f);
      const float is2 = rsqrtf(var + 1e-5f) * L2T;
      float S = 0.f;
      for (int i = 0; i < 100; i++) S += exp2f((fb[base + i*stride] - m) * is2);
      const float cc = m*is2 + log2f(S);
      if (isCol){ isc[line] = is2; ccs[line] = cc; }
      else      { isr[line] = is2; ccr[line] = cc; }
    }
  }
  __syncthreads();
  {
    const int line = t & 127;
    if (line < 100){
      if (t < 128){
        float a = 0.f;
        for (int k = 0; k < 100; k++)
          a += exp2f(fb[line*101 + k] * isc[k] - ccs[k]);
        asq[(size_t)pair*256 + line] = a;
        asqh[(size_t)pair*256 + line] = (f16)a;
      } else {
        float a = 0.f;
        for (int k = 0; k < 100; k++)
          a += exp2f(fb[k*101 + line] * isr[k] - ccr[k]);
        asq[(size_t)pair*256 + 128 + line] = a;
        asqh[(size_t)pair*256 + 128 + line] = (f16)a;
      }
    } else {
      asq[(size_t)pair*256 + t] = 0.f;
      asqh[(size_t)pair*256 + t] = (f16)0;
    }
  }
}

// ---------------- spqp: 350 blocks; all-f16 fragment loads on sp path ----------------
__global__ __launch_bounds__(256) void k_spqp(
    const f16* __restrict__ spt16, const float* __restrict__ qry,
    const f16* __restrict__ asqh, float* __restrict__ P)
{
  const int b = blockIdx.x;
  const int t = threadIdx.x, l = t & 63, wid = t >> 6;
  const int r16 = l & 15, kb = (l >> 4) & 3;

  if (b < 50){
    const int w = b / 10, c0 = (b % 10) * 64;
    const int c = c0 + wid*16 + r16;
    f16x8 bf[4];
    #pragma unroll
    for (int kt = 0; kt < 4; kt++)
      bf[kt] = *(const f16x8*)(spt16 + ((size_t)w*640 + c)*128 + kt*32 + kb*8);
    #pragma unroll 1
    for (int mt = 0; mt < 10; mt++){
      const int qr = mt*16 + r16;   // rows >=150 read garbage (allocated); outputs guarded
      f32x4 acc = {0.f,0.f,0.f,0.f};
      #pragma unroll
      for (int kt = 0; kt < 4; kt++){
        const f16x8 au = *(const f16x8*)(asqh + (size_t)(qr*5 + w)*256 + kt*32 + kb*8);
        acc = __builtin_amdgcn_mfma_f32_16x16x32_f16(au, bf[kt], acc, 0, 0, 0);
      }
      #pragma unroll
      for (int r = 0; r < 4; r++){
        const int q2 = mt*16 + kb*4 + r;
        if (q2 < 150) P[(size_t)(q2*5 + w)*1280 + c0 + wid*16 + (l & 15)] = acc[r];
      }
    }
  } else {
    const int idx = b - 50, q = idx >> 1, chalf = idx & 1;
    f16x8 af4[4];
    #pragma unroll
    for (int kt = 0; kt < 4; kt++)
      af4[kt] = *(const f16x8*)(asqh + (size_t)(q*5 + r16)*256 + 128 + kt*32 + kb*8);
    #pragma unroll 1
    for (int nt = chalf*20 + wid; nt < chalf*20 + 20; nt += 4){
      const int c = nt*16 + r16;
      f32x4 acc = {0.f,0.f,0.f,0.f};
      #pragma unroll
      for (int kt = 0; kt < 4; kt++){
        const int kbase = kt*32 + kb*8;
        float v[8];
        #pragma unroll
        for (int j = 0; j < 8; j++){
          const int k = kbase + j;
          v[j] = (k < 100) ? qry[(size_t)q*64000 + (size_t)c*100 + k] : 0.f;
        }
        union { f16x8 v8; f16x2 h2[4]; } uu;
        #pragma unroll
        for (int j2 = 0; j2 < 4; j2++) uu.h2[j2] = pkrtz(v[2*j2], v[2*j2+1]);
        acc = __builtin_amdgcn_mfma_f32_16x16x32_f16(af4[kt], uu.v8, acc, 0, 0, 0);
      }
      #pragma unroll
      for (int r = 0; r < 4; r++){
        const int w2 = kb*4 + r;
        if (w2 < 5) P[(size_t)(q*5 + w2)*1280 + 640 + nt*16 + (l & 15)] = acc[r];
      }
    }
  }
}

// ---------------- cos: mean-correct + cosine per pair ----------------
__global__ __launch_bounds__(256) void k_cos(
    const float* __restrict__ P, const float* __restrict__ asq,
    const float* __restrict__ sptm, const float* __restrict__ qrym,
    float* __restrict__ out)
{
  __shared__ float pred[4];
  __shared__ float MsMq[2];
  __shared__ float red[12];
  const int pair = blockIdx.x;
  const int q = pair / WAYT, w = pair % WAYT;
  const int t = threadIdx.x, wid = t >> 6;

  float pm = 0.f;
  if (t < 100) pm = asq[(size_t)pair*256 + t] * sptm[w*100 + t];
  else if (t >= 128 && t < 228) pm = asq[(size_t)pair*256 + t] * qrym[q*100 + (t - 128)];
  #pragma unroll
  for (int m = 1; m < 64; m <<= 1) pm += __shfl_xor(pm, m);
  if ((t & 63) == 0) pred[wid] = pm;
  __syncthreads();
  if (t == 0) MsMq[0] = pred[0] + pred[1];
  if (t == 1) MsMq[1] = pred[2] + pred[3];
  __syncthreads();
  const float Ms = MsMq[0], Mq = MsMq[1];

  float d0 = 0.f, d1 = 0.f, d2 = 0.f;
  for (int c = t; c < 640; c += 256){
    const float sp = P[(size_t)pair*1280 + c] - Ms;
    const float qp = P[(size_t)pair*1280 + 640 + c] - Mq;
    d0 += sp*qp; d1 += sp*sp; d2 += qp*qp;
  }
  #pragma unroll
  for (int m = 1; m < 64; m <<= 1){
    d0 += __shfl_xor(d0, m); d1 += __shfl_xor(d1, m); d2 += __shfl_xor(d2, m);
  }
  if ((t & 63) == 0){ red[wid*3+0] = d0; red[wid*3+1] = d1; red[wid*3+2] = d2; }
  __syncthreads();
  if (t == 0){
    float e0 = 0.f, e1 = 0.f, e2 = 0.f;
    #pragma unroll
    for (int k = 0; k < 4; k++){ e0 += red[k*3]; e1 += red[k*3+1]; e2 += red[k*3+2]; }
    const float den = fmaxf(sqrtf(e1), 1e-8f) * fmaxf(sqrtf(e2), 1e-8f);
    out[pair] = (e0 / den) * 5.0f;
  }
}

extern "C" void kernel_launch(void* const* d_in, const int* in_sizes, int n_in,
                              void* d_out, int out_size, void* d_ws, size_t ws_size,
                              hipStream_t stream)
{
  (void)in_sizes; (void)n_in; (void)out_size; (void)ws_size;
  const float* spt = (const float*)d_in[0];
  const float* qry = (const float*)d_in[1];
  const float* Wc  = (const float*)d_in[2];
  const float* gc  = (const float*)d_in[3];
  const float* bc  = (const float*)d_in[4];

  float* ws    = (float*)d_ws;
  float* cp    = ws;                          // 256
  float* wsum  = ws + 256;                    // 64
  float* sptm  = ws + 320;                    // 500
  float* qrym  = ws + 820;                    // 15000 -> pad 15872
  f16*  Apack  = (f16*)(ws + 15872);          // 2560 f16
  f16*  Wf2    = (f16*)(ws + 17152);          // 256 f16
  f16*  W65    = (f16*)(ws + 17408);          // 51200 f16
  f16*  MuF    = (f16*)(ws + 43008);          // 14336 f16
  f16*  MhF    = (f16*)(ws + 50176);          // 14336 f16
  f16*  s16    = (f16*)(ws + 57344);          // 35840 f16
  f16*  q16    = (f16*)(ws + 75264);          // 1075200 f16
  f16*  z      = (f16*)(ws + 612864);         // 7.5M f16
  f16*  F      = (f16*)(ws + 4362864);        // 7.5M f16
  f16*  spt16  = (f16*)(ws + 8112864);        // 409600 f16 (end ~33.3 MB)
  // aliases (lifetime-disjoint):
  float* asq   = ws + 75264;                  // over q16 (dead after k_z); 192000 f32
  f16*  asqh   = (f16*)(ws + 75264 + 192000); // over q16; 800x256 f16 (rows >=750 unwritten, reads guarded by output masks)
  float* P     = ws + 612864;                 // over z (dead after k_l1); 960000 f32

  k_prep_all<<<241, 256, 0, stream>>>(
      spt, Wc,
      (const float*)d_in[5],  (const float*)d_in[6],  (const float*)d_in[7],
      (const float*)d_in[8],  (const float*)d_in[9],  (const float*)d_in[10],
      (const float*)d_in[11], (const float*)d_in[12], (const float*)d_in[13],
      (const float*)d_in[14], (const float*)d_in[15], (const float*)d_in[16],
      (const float*)d_in[17], (const float*)d_in[18], (const float*)d_in[19],
      (const float*)d_in[20], (const float*)d_in[21], (const float*)d_in[22],
      cp, Apack, Wf2, MuF, MhF, W65, wsum, spt16);
  k_feat<<<620, 256, 0, stream>>>(spt, qry, W65, wsum, gc, bc, s16, q16, sptm, qrym);
  k_z<<<NQT*WAYT, 256, 0, stream>>>(s16, q16, cp, MuF, MhF, z);
  {
    dim3 grid(10, NQT*WAYT);
    k_l1<<<grid, 256, 0, stream>>>(z, cp, Apack, Wf2, F);
  }
  k_attn_a<<<NQT*WAYT, 256, 0, stream>>>(F, asq, asqh);
  k_spqp<<<350, 256, 0, stream>>>(spt16, qry, asqh, P);
  k_cos<<<NQT*WAYT, 256, 0, stream>>>(P, asq, sptm, qrym, (float*)d_out);
}

// Round 12
// 224.718 us; speedup vs baseline: 1.4035x; 1.0094x over previous
//
#include <hip/hip_runtime.h>
#include <cstdint>
#include <cstddef>

#define NQT   150
#define WAYT  5
#define CCH   640

typedef _Float16 f16;
typedef _Float16 f16x2 __attribute__((ext_vector_type(2)));
typedef _Float16 f16x4 __attribute__((ext_vector_type(4)));
typedef _Float16 f16x8 __attribute__((ext_vector_type(8)));
typedef float    f32x4 __attribute__((ext_vector_type(4)));

static __device__ __forceinline__ f16x2 pkrtz(float a, float b){
  return __builtin_bit_cast(f16x2, __builtin_amdgcn_cvt_pkrtz(a, b));
}

// const-pack offsets (floats)
#define CP_A     0
#define CP_B     16
#define CP_G2    32
#define CP_B2    48
#define CP_W20   64
#define CP_W10   73
#define CP_SC    82
#define CP_T9    96
#define GS_STRIDE 1076

// stencil matrix value: Mat[k = src pos][n = dst pos], 10x10 grid, 3x3 taps
static __device__ __forceinline__ float stencil9(int k, int n, const float* __restrict__ w9){
  if (k >= 100 || n >= 100) return 0.f;
  const int a = n/10, b = n%10, a2 = k/10, b2 = k%10;
  const int dA = a2 - a + 1, dB = b2 - b + 1;
  if ((unsigned)dA > 2u || (unsigned)dB > 2u) return 0.f;
  return w9[dA*3 + dB];
}

// ---------------- prep (merged; grid 241) ----------------
__global__ __launch_bounds__(256) void k_prep_all(
    const float* __restrict__ spt, const float* __restrict__ W,
    const float* __restrict__ s0_w2, const float* __restrict__ s0_g2, const float* __restrict__ s0_b2,
    const float* __restrict__ s0_w1, const float* __restrict__ s0_g1, const float* __restrict__ s0_b1,
    const float* __restrict__ s0_wp, const float* __restrict__ s0_gp, const float* __restrict__ s0_bp,
    const float* __restrict__ s1_w2, const float* __restrict__ s1_g2, const float* __restrict__ s1_b2,
    const float* __restrict__ s1_w1, const float* __restrict__ s1_g1, const float* __restrict__ s1_b1,
    const float* __restrict__ s1_wp, const float* __restrict__ s1_gp, const float* __restrict__ s1_bp,
    float* __restrict__ cp, f16* __restrict__ Apack, f16* __restrict__ Wf2,
    f16* __restrict__ MuF, f16* __restrict__ MhF,
    f16* __restrict__ W65, float* __restrict__ wsum, f16* __restrict__ spt16)
{
  const int b = blockIdx.x, t = threadIdx.x;
  if (b == 0){
    for (int e = t; e < 2560; e += 256){
      int p = e / 512, r = e % 512, l = r / 8, j = r % 8;
      int kb = l >> 4;
      int tap = 2*p + (kb >> 1);
      int cin = (kb & 1)*8 + j;
      int co = l & 15;
      float v = 0.f;
      if (tap <= 8){
        int du = tap / 3, dv = tap % 3;
        v = s1_w2[((co*16 + cin)*3 + du)*3 + dv];
      }
      Apack[e] = (f16)v;
    }
    const float gp1 = s1_gp[0];
    {
      int l = t >> 2, j = t & 3;
      int tap = l & 15, ci = ((l >> 4) << 2) + j;
      float v = 0.f;
      if (tap <= 8){
        for (int co = 0; co < 16; co++)
          v += gp1 * s1_wp[co] * s1_g1[co] * s1_w1[(co*16 + ci)*9 + tap];
      }
      Wf2[t] = (f16)v;
    }
    if (t < 144){
      int tap = t / 16, co = t % 16;
      float s = 0.f;
      for (int cin = 0; cin < 16; cin++){
        float wv = (float)(f16)s1_w2[((co*16 + cin)*3 + tap/3)*3 + tap%3];
        float rb = fmaxf((float)(f16)s0_bp[cin], 0.f);
        s += wv * rb;
      }
      cp[CP_T9 + t] = s;
    }
    if (t < 16){
      cp[CP_A + t]  = s0_gp[t] * s0_wp[t];
      cp[CP_B + t]  = s0_bp[t];
      cp[CP_G2 + t] = s1_g2[t];
      cp[CP_B2 + t] = s1_b2[t];
    }
    if (t < 9){ cp[CP_W20 + t] = s0_w2[t]; cp[CP_W10 + t] = s0_w1[t]; }
    if (t == 0){
      cp[CP_SC + 0] = s0_g2[0]; cp[CP_SC + 1] = s0_b2[0];
      cp[CP_SC + 2] = s0_g1[0]; cp[CP_SC + 3] = s0_b1[0];
      float kk = 0.f;
      for (int co = 0; co < 16; co++) kk += s1_wp[co] * s1_b1[co];
      cp[CP_SC + 4] = gp1 * kk + s1_bp[0];
    }
  } else if (b <= 14){
    const bool isMu = (b <= 7);
    f16* dst = isMu ? MuF : MhF;
    const float* w9 = isMu ? s0_w2 : s0_w1;
    const int base = (isMu ? (b-1) : (b-8)) * 2048;
    #pragma unroll
    for (int e2 = 0; e2 < 8; e2++){
      const int idx = base + e2*256 + t;
      const int j = idx & 7, l2 = (idx >> 3) & 63, ktnt = idx >> 9;
      const int kt = ktnt & 3, nt = ktnt >> 2;
      const int n = nt*16 + (l2 & 15);
      const int k = kt*32 + ((l2 >> 4) & 3)*8 + j;
      dst[idx] = (f16)stencil9(k, n, w9);
    }
  } else if (b <= 39){
    const int base = (b - 15) * 2048;
    #pragma unroll
    for (int e2 = 0; e2 < 8; e2++){
      const int idx = base + e2*256 + t;
      const int row = idx / 640, c = idx - row*640;
      float v = 0.f;
      if (row < 64) v = W[row*640 + c];
      else if (row == 64) v = 1.f;
      W65[idx] = (f16)v;
    }
  } else if (b == 40){
    const int o = t >> 2, qq = t & 3;
    float s = 0.f;
    for (int c = qq; c < 640; c += 4) s += W[o*640 + c];
    s += __shfl_xor(s, 1); s += __shfl_xor(s, 2);
    if (qq == 0) wsum[o] = s;
  } else {
    // spt16: [5][640][128] f16, k>=100 zero
    const int base = (b - 41) * 2048;
    #pragma unroll
    for (int e2 = 0; e2 < 8; e2++){
      const int idx = base + e2*256 + t;
      const int w = idx / 81920, r = idx % 81920;
      const int c = r >> 7, k = r & 127;
      spt16[idx] = (k < 100) ? (f16)spt[(size_t)w*64000 + c*100 + k] : (f16)0;
    }
  }
}

// ---------------- feat: 620 blocks; GEMM Y[80][32] per block ----------------
__device__ __forceinline__ void feat_stage4(const float* __restrict__ x, int pixoff, int kt,
                                            f16* __restrict__ dst, int t){
  if (t < 224){
    const int cc = t / 7, qd = t % 7;
    float4 v4 = make_float4(0.f, 0.f, 0.f, 0.f);
    if (pixoff + qd*4 + 4 <= 100)
      v4 = *(const float4*)(x + (size_t)(kt*32 + cc)*100 + pixoff + qd*4);
    dst[(qd*4+0)*40 + cc] = (f16)v4.x;
    dst[(qd*4+1)*40 + cc] = (f16)v4.y;
    dst[(qd*4+2)*40 + cc] = (f16)v4.z;
    dst[(qd*4+3)*40 + cc] = (f16)v4.w;
  }
}

__global__ __launch_bounds__(256) void k_feat(
    const float* __restrict__ spt, const float* __restrict__ qry,
    const f16* __restrict__ W65, const float* __restrict__ wsum,
    const float* __restrict__ gg, const float* __restrict__ bb,
    f16* __restrict__ s16, f16* __restrict__ q16,
    float* __restrict__ sptm, float* __restrict__ qrym)
{
  __shared__ f16 Xs[2][32*40];
  __shared__ float Ys[32*85];
  __shared__ float sg[64], sb[64], sw[64];
  const int b = blockIdx.x;
  const int n = b >> 2, quarter = b & 3;
  const int pixbase = quarter * 28;
  const float* x; f16* out16; float* mout;
  if (n < 5){ x = spt + (size_t)n*64000; out16 = s16 + (size_t)n*7168; mout = sptm + n*100; }
  else { x = qry + (size_t)(n-5)*64000; out16 = q16 + (size_t)(n-5)*7168; mout = qrym + (size_t)(n-5)*100; }
  const int t = threadIdx.x, l = t & 63, wid = t >> 6;
  const int r16 = l & 15, kbq = (l >> 4) & 3;

  if (t < 40){
    const f16x8 z8 = {(f16)0,(f16)0,(f16)0,(f16)0,(f16)0,(f16)0,(f16)0,(f16)0};
    const int bu = t / 20, rr = (t % 20) / 5, o = t % 5;
    *(f16x8*)(Xs[bu] + (28 + rr)*40 + o*8) = z8;
  }
  if (t >= 64 && t < 128){ sg[t-64] = gg[t-64]; sb[t-64] = bb[t-64]; sw[t-64] = wsum[t-64]; }

  int mts[3], nts[3];
  #pragma unroll
  for (int s = 0; s < 3; s++){ const int mn = wid + s*4; mts[s] = mn >> 1; nts[s] = mn & 1; }
  f32x4 acc[3];
  #pragma unroll
  for (int s = 0; s < 3; s++) acc[s] = (f32x4){0.f,0.f,0.f,0.f};

  feat_stage4(x, pixbase, 0, Xs[0], t);
  __syncthreads();
  for (int kt = 0; kt < 20; kt++){
    if (kt < 19) feat_stage4(x, pixbase, kt+1, Xs[(kt+1)&1], t);
    const f16* xb = Xs[kt&1];
    #pragma unroll
    for (int s = 0; s < 3; s++){
      const int mn = wid + s*4;
      if (mn < 10){
        const f16x8 a8 = *(const f16x8*)(W65 + (size_t)(mts[s]*16 + r16)*640 + kt*32 + kbq*8);
        const f16x8 b8 = *(const f16x8*)(xb + (nts[s]*16 + r16)*40 + kbq*8);
        acc[s] = __builtin_amdgcn_mfma_f32_16x16x32_f16(a8, b8, acc[s], 0, 0, 0);
      }
    }
    __syncthreads();
  }
  #pragma unroll
  for (int s = 0; s < 3; s++){
    const int mn = wid + s*4;
    if (mn < 10){
      const int col = nts[s]*16 + r16, rb = mts[s]*16 + kbq*4;
      #pragma unroll
      for (int r = 0; r < 4; r++) Ys[col*85 + rb + r] = acc[s][r];
    }
  }
  __syncthreads();

  if (t < 224){
    const int pixl = t >> 3, oo = t & 7;
    const int pixg = pixbase + pixl;
    const bool ok = (pixg < 100);
    const float m = Ys[pixl*85 + 64] * (1.f/640.f);
    float yr[8]; float ssq = 0.f;
    #pragma unroll
    for (int j = 0; j < 8; j++){
      const int o = oo*8 + j;
      float yv = 0.f;
      if (ok) yv = fmaxf(sg[o]*(Ys[pixl*85 + o] - sw[o]*m) + sb[o], 0.f);
      yr[j] = yv; ssq += yv*yv;
    }
    ssq += __shfl_xor(ssq, 1); ssq += __shfl_xor(ssq, 2); ssq += __shfl_xor(ssq, 4);
    const float inv = ok ? (1.f / fmaxf(sqrtf(ssq), 1e-8f)) : 0.f;
    #pragma unroll
    for (int j2 = 0; j2 < 4; j2++){
      f16x2 hv = { (f16)(yr[2*j2]*inv), (f16)(yr[2*j2+1]*inv) };
      *(f16x2*)(out16 + (size_t)pixg*64 + oo*8 + 2*j2) = hv;
    }
    if (oo == 0 && ok) mout[pixg] = m;
  }
}

// ---------------- k_z: corr + layer0 as three MFMA GEMMs -> z (f16) ----------------
__global__ __launch_bounds__(256) void k_z(
    const f16* __restrict__ s16, const f16* __restrict__ q16,
    const float* __restrict__ cp, const f16* __restrict__ MuF, const f16* __restrict__ MhF,
    f16* __restrict__ z)
{
  __shared__ __align__(16) f16 smz[112*120 + 112*120 + 16];
  f16* cbT = smz;
  f16* tS  = smz + 112*120;
  const int pair = blockIdx.x;
  const int q = pair / WAYT, w = pair % WAYT;
  const int t = threadIdx.x, l = t & 63, wid = t >> 6;
  const int r16 = l & 15, kb = (l >> 4) & 3;

  {
    const f16x8 z8 = {(f16)0,(f16)0,(f16)0,(f16)0,(f16)0,(f16)0,(f16)0,(f16)0};
    if (t < 112){
      *(f16x8*)(cbT + t*120 + 112) = z8;
      *(f16x8*)(tS  + t*120 + 112) = z8;
    }
    if (t < 16) tS[112*120 + t] = (f16)0;
    if (t >= 240 && t < 248) tS[t - 240] = (f16)0;
  }

  const f16* sbase = s16 + (size_t)w * 7168;
  const f16* qbase = q16 + (size_t)q * 7168;

  for (int mn = wid; mn < 49; mn += 4){
    const int mt = mn / 7, nt = mn - (mn/7)*7;
    const f16x8 a0 = *(const f16x8*)(sbase + (mt*16 + r16)*64 + kb*8);
    const f16x8 a1 = *(const f16x8*)(sbase + (mt*16 + r16)*64 + 32 + kb*8);
    const f16x8 b0 = *(const f16x8*)(qbase + (nt*16 + r16)*64 + kb*8);
    const f16x8 b1 = *(const f16x8*)(qbase + (nt*16 + r16)*64 + 32 + kb*8);
    f32x4 acc = {0.f,0.f,0.f,0.f};
    acc = __builtin_amdgcn_mfma_f32_16x16x32_f16(a0, b0, acc, 0, 0, 0);
    acc = __builtin_amdgcn_mfma_f32_16x16x32_f16(a1, b1, acc, 0, 0, 0);
    union { f16x4 v4; f16x2 h2[2]; } hv;
    hv.h2[0] = pkrtz(acc[0], acc[1]);
    hv.h2[1] = pkrtz(acc[2], acc[3]);
    *(f16x4*)(cbT + (nt*16 + r16)*120 + mt*16 + kb*4) = hv.v4;
  }
  __syncthreads();

  const float g20 = cp[CP_SC+0], b20 = cp[CP_SC+1];
  for (int mn = wid; mn < 49; mn += 4){
    const int mt = mn / 7, nt = mn - (mn/7)*7;
    f32x4 acc = {0.f,0.f,0.f,0.f};
    #pragma unroll
    for (int kt = 0; kt < 4; kt++){
      const f16x8 a8 = *(const f16x8*)(cbT + (mt*16 + r16)*120 + kt*32 + kb*8);
      const f16x8 b8 = *(const f16x8*)(MuF + (size_t)(nt*4 + kt)*512 + l*8);
      acc = __builtin_amdgcn_mfma_f32_16x16x32_f16(a8, b8, acc, 0, 0, 0);
    }
    union { f16x4 v4; f16x2 h2[2]; } hv;
    hv.h2[0] = pkrtz(fmaxf(g20*acc[0] + b20, 0.f), fmaxf(g20*acc[1] + b20, 0.f));
    hv.h2[1] = pkrtz(fmaxf(g20*acc[2] + b20, 0.f), fmaxf(g20*acc[3] + b20, 0.f));
    *(f16x4*)(tS + (nt*16 + r16)*120 + mt*16 + kb*4) = hv.v4;
  }
  __syncthreads();

  const float g10 = cp[CP_SC+2], b10 = cp[CP_SC+3];
  for (int mn = wid; mn < 49; mn += 4){
    const int mt = mn / 7, nt = mn - (mn/7)*7;
    f32x4 acc = {0.f,0.f,0.f,0.f};
    #pragma unroll
    for (int kt = 0; kt < 4; kt++){
      const f16x8 a8 = *(const f16x8*)(tS + (mt*16 + r16)*120 + kt*32 + kb*8);
      const f16x8 b8 = *(const f16x8*)(MhF + (size_t)(nt*4 + kt)*512 + l*8);
      acc = __builtin_amdgcn_mfma_f32_16x16x32_f16(a8, b8, acc, 0, 0, 0);
    }
    const int hw = nt*16 + r16;
    if (hw < 100){
      #pragma unroll
      for (int r = 0; r < 4; r++){
        const int uv = mt*16 + kb*4 + r;
        if (uv < 100) z[(size_t)pair*10000 + uv*100 + hw] = (f16)(g10*acc[r] + b10);
      }
    }
  }
}

// ---------------- k_l1: round-8 math; i-loop unroll 2 for ILP ----------------
__global__ __launch_bounds__(256, 6) void k_l1(
    const f16* __restrict__ z, const float* __restrict__ cp,
    const f16* __restrict__ Apack, const f16* __restrict__ Wf2, f16* __restrict__ F)
{
  __shared__ f16 z3[3*1216];
  __shared__ f16 Gs[9*GS_STRIDE];
  const int u = blockIdx.x, pair = blockIdx.y;
  const int t = threadIdx.x, l = t & 63, wid = t >> 6;
  const int r16 = l & 15, kb = (l >> 4) & 3;
  const int khi = kb & 1, half = kb >> 1;

  for (int e = t; e < 1824; e += 256){
    const int du = e / 608, c2 = e - du*608;
    const int ur = u + du - 1;
    const int colb = c2*2;
    const int g = colb - 100;
    f16x2 v = {(f16)0, (f16)0};
    if (ur >= 0 && ur <= 9 && g >= 0 && g < 1000)
      v = *(const f16x2*)(z + (size_t)pair*10000 + ur*1000 + g);
    *(f16x2*)(z3 + du*1216 + colb) = v;
  }

  f16x2 Ac2[4], Bc2[4];
  {
    const float4 a4a = ((const float4*)(cp + CP_A))[khi*2];
    const float4 a4b = ((const float4*)(cp + CP_A))[khi*2+1];
    const float4 b4a = ((const float4*)(cp + CP_B))[khi*2];
    const float4 b4b = ((const float4*)(cp + CP_B))[khi*2+1];
    Ac2[0] = (f16x2){(f16)a4a.x,(f16)a4a.y}; Ac2[1] = (f16x2){(f16)a4a.z,(f16)a4a.w};
    Ac2[2] = (f16x2){(f16)a4b.x,(f16)a4b.y}; Ac2[3] = (f16x2){(f16)a4b.z,(f16)a4b.w};
    Bc2[0] = (f16x2){(f16)b4a.x,(f16)b4a.y}; Bc2[1] = (f16x2){(f16)b4a.z,(f16)b4a.w};
    Bc2[2] = (f16x2){(f16)b4b.x,(f16)b4b.y}; Bc2[3] = (f16x2){(f16)b4b.z,(f16)b4b.w};
  }
  f16x8 af[5];
  #pragma unroll
  for (int p = 0; p < 5; p++) af[p] = ((const f16x8*)Apack)[p*64 + l];
  const f16x4 wf = ((const f16x4*)Wf2)[l];

  float gv[4], bm[4], bv0[4], bv9[4];
  #pragma unroll
  for (int r = 0; r < 4; r++){
    const int co = kb*4 + r;
    gv[r] = cp[CP_G2 + co];
    const float b0 = cp[CP_B2 + co];
    float c0 = 0.f, cv0 = 0.f, cv9 = 0.f;
    #pragma unroll
    for (int du = 0; du < 3; du++){
      const int ur = u + du - 1;
      const float t0 = cp[CP_T9 + (du*3+0)*16 + co];
      const float t1 = cp[CP_T9 + (du*3+1)*16 + co];
      const float t2 = cp[CP_T9 + (du*3+2)*16 + co];
      if (ur < 0 || ur > 9) c0 += t0 + t1 + t2;
      else { cv0 += t0; cv9 += t2; }
    }
    bm[r]  = b0 - gv[r]*c0;
    bv0[r] = bm[r] - gv[r]*cv0;
    bv9[r] = bm[r] - gv[r]*cv9;
  }
  int zoffE[5];
  #pragma unroll
  for (int p = 0; p < 5; p++){
    const int tap = 2*p + half;
    const int du = (tap <= 8) ? tap/3 : 0;
    const int dv = (tap <= 8) ? tap%3 : 0;
    zoffE[p] = du*1216 + dv*100;
  }
  __syncthreads();

  const f16x2 zero2 = {(f16)0, (f16)0};
  #pragma unroll 2
  for (int i = 0; i < 16; i++){
    const int cbase = wid*256 + i*16;
    if (cbase >= 1008) break;
    const int c = cbase + r16;
    const int v = (c * 5243) >> 19;
    f32x4 acc = {0.f,0.f,0.f,0.f};
    #pragma unroll
    for (int p = 0; p < 5; p++){
      const f16 zv = z3[zoffE[p] + c];
      const f16x2 zz = {zv, zv};
      union { f16x8 v8; f16x2 h2[4]; } bu;
      #pragma unroll
      for (int j2 = 0; j2 < 4; j2++){
        f16x2 r2 = Ac2[j2] * zz + Bc2[j2];
        bu.h2[j2] = __builtin_elementwise_max(r2, zero2);
      }
      acc = __builtin_amdgcn_mfma_f32_16x16x32_f16(af[p], bu.v8, acc, 0, 0, 0);
    }
    const bool isv0 = (v == 0), isv9 = (v == 9);
    float rr[4];
    #pragma unroll
    for (int r = 0; r < 4; r++){
      const float bsel = isv0 ? bv0[r] : (isv9 ? bv9[r] : bm[r]);
      rr[r] = fmaxf(fmaf(gv[r], acc[r], bsel), 0.f);
    }
    union { f16x4 v4; f16x2 h2[2]; } t1u;
    t1u.h2[0] = pkrtz(rr[0], rr[1]);
    t1u.h2[1] = pkrtz(rr[2], rr[3]);
    f32x4 g = {0.f,0.f,0.f,0.f};
    g = __builtin_amdgcn_mfma_f32_16x16x16f16(wf, t1u.v4, g, 0, 0, 0);
    #pragma unroll
    for (int r = 0; r < 4; r++){
      const int tap = kb*4 + r;
      if (tap <= 8) Gs[tap*GS_STRIDE + 16 + c] = (f16)g[r];
    }
  }
  __syncthreads();

  const float Kc = cp[CP_SC+4];
  #pragma unroll 1
  for (int oo = 0; oo < 4; oo++){
    const int c = t + oo*256;
    if (c < 1000){
      const int hw = c - ((c * 5243) >> 19) * 100;
      const int h = (hw * 205) >> 11, w2 = hw - h*10;
      float o = Kc;
      #pragma unroll
      for (int dh = 0; dh < 3; dh++){
        #pragma unroll
        for (int dw = 0; dw < 3; dw++){
          const bool okg = ((unsigned)(h + dh - 1) <= 9u) && ((unsigned)(w2 + dw - 1) <= 9u);
          const float gvv = (float)Gs[(dh*3+dw)*GS_STRIDE + 16 + c + (dh-1)*10 + (dw-1)];
          o += okg ? gvv : 0.f;
        }
      }
      F[(size_t)pair*10000 + u*1000 + c] = (f16)o;
    }
  }
}

// ---------------- attn_a: gnorm + softmax -> asq (f32) + asqh (f16), zero-padded ----------------
__global__ __launch_bounds__(256) void k_attn_a(const f16* __restrict__ F,
                                                float* __restrict__ asq, f16* __restrict__ asqh)
{
  __shared__ float fb[100*101 + 4];
  __shared__ float isc[100], ccs[100], isr[100], ccr[100];
  const int pair = blockIdx.x;
  const int t = threadIdx.x;
  const float L2T = 1.4426950408889634f * 0.2f;

  for (int e = t; e < 10000; e += 256)
    fb[(e/100)*101 + (e%100)] = (float)F[(size_t)pair*10000 + e];
  __syncthreads();

  {
    const int line = t & 127;
    const bool isCol = t < 128;
    if (line < 100){
      const int base = isCol ? line : line*101;
      const int stride = isCol ? 101 : 1;
      float s = 0.f, ss = 0.f;
      for (int i = 0; i < 100; i++){ const float x = fb[base + i*stride]; s += x; ss += x*x; }
      const float m = s * 0.01f;
      const float var = (ss - 100.f*m*m) * (1.f/99.f);
      const float is2 = rsqrtf(var + 1e-5f) * L2T;
      float S = 0.f;
      for (int i = 0; i < 100; i++) S += exp2f((fb[base + i*stride] - m) * is2);
      const float cc = m*is2 + log2f(S);
      if (isCol){ isc[line] = is2; ccs[line] = cc; }
      else      { isr[line] = is2; ccr[line] = cc; }
    }
  }
  __syncthreads();
  {
    const int line = t & 127;
    if (line < 100){
      if (t < 128){
        float a = 0.f;
        for (int k = 0; k < 100; k++)
          a += exp2f(fb[line*101 + k] * isc[k] - ccs[k]);
        asq[(size_t)pair*256 + line] = a;
        asqh[(size_t)pair*256 + line] = (f16)a;
      } else {
        float a = 0.f;
        for (int k = 0; k < 100; k++)
          a += exp2f(fb[k*101 + line] * isr[k] - ccr[k]);
        asq[(size_t)pair*256 + 128 + line] = a;
        asqh[(size_t)pair*256 + 128 + line] = (f16)a;
      }
    } else {
      asq[(size_t)pair*256 + t] = 0.f;
      asqh[(size_t)pair*256 + t] = (f16)0;
    }
  }
}

// ---------------- spqp: 350 blocks; f16 sp path, vectorized qp loads ----------------
__global__ __launch_bounds__(256) void k_spqp(
    const f16* __restrict__ spt16, const float* __restrict__ qry,
    const f16* __restrict__ asqh, float* __restrict__ P)
{
  const int b = blockIdx.x;
  const int t = threadIdx.x, l = t & 63, wid = t >> 6;
  const int r16 = l & 15, kb = (l >> 4) & 3;

  if (b < 50){
    const int w = b / 10, c0 = (b % 10) * 64;
    const int c = c0 + wid*16 + r16;
    f16x8 bf[4];
    #pragma unroll
    for (int kt = 0; kt < 4; kt++)
      bf[kt] = *(const f16x8*)(spt16 + ((size_t)w*640 + c)*128 + kt*32 + kb*8);
    #pragma unroll 1
    for (int mt = 0; mt < 10; mt++){
      const int qr = mt*16 + r16;   // rows >=150 read garbage (allocated); outputs guarded
      f32x4 acc = {0.f,0.f,0.f,0.f};
      #pragma unroll
      for (int kt = 0; kt < 4; kt++){
        const f16x8 au = *(const f16x8*)(asqh + (size_t)(qr*5 + w)*256 + kt*32 + kb*8);
        acc = __builtin_amdgcn_mfma_f32_16x16x32_f16(au, bf[kt], acc, 0, 0, 0);
      }
      #pragma unroll
      for (int r = 0; r < 4; r++){
        const int q2 = mt*16 + kb*4 + r;
        if (q2 < 150) P[(size_t)(q2*5 + w)*1280 + c0 + wid*16 + (l & 15)] = acc[r];
      }
    }
  } else {
    const int idx = b - 50, q = idx >> 1, chalf = idx & 1;
    f16x8 af4[4];
    #pragma unroll
    for (int kt = 0; kt < 4; kt++)
      af4[kt] = *(const f16x8*)(asqh + (size_t)(q*5 + r16)*256 + 128 + kt*32 + kb*8);
    #pragma unroll 1
    for (int nt = chalf*20 + wid; nt < chalf*20 + 20; nt += 4){
      const int c = nt*16 + r16;
      const float* qr = qry + (size_t)q*64000 + (size_t)c*100;
      f32x4 acc = {0.f,0.f,0.f,0.f};
      #pragma unroll
      for (int kt = 0; kt < 4; kt++){
        const int kbase = kt*32 + kb*8;
        float v[8];
        if (kbase + 8 <= 100){
          const float4 v4a = *(const float4*)(qr + kbase);
          const float4 v4b = *(const float4*)(qr + kbase + 4);
          v[0]=v4a.x; v[1]=v4a.y; v[2]=v4a.z; v[3]=v4a.w;
          v[4]=v4b.x; v[5]=v4b.y; v[6]=v4b.z; v[7]=v4b.w;
        } else if (kbase == 96){
          const float4 v4a = *(const float4*)(qr + 96);
          v[0]=v4a.x; v[1]=v4a.y; v[2]=v4a.z; v[3]=v4a.w;
          v[4]=0.f; v[5]=0.f; v[6]=0.f; v[7]=0.f;
        } else {
          #pragma unroll
          for (int j = 0; j < 8; j++) v[j] = 0.f;
        }
        union { f16x8 v8; f16x2 h2[4]; } uu;
        #pragma unroll
        for (int j2 = 0; j2 < 4; j2++) uu.h2[j2] = pkrtz(v[2*j2], v[2*j2+1]);
        acc = __builtin_amdgcn_mfma_f32_16x16x32_f16(af4[kt], uu.v8, acc, 0, 0, 0);
      }
      #pragma unroll
      for (int r = 0; r < 4; r++){
        const int w2 = kb*4 + r;
        if (w2 < 5) P[(size_t)(q*5 + w2)*1280 + 640 + nt*16 + (l & 15)] = acc[r];
      }
    }
  }
}

// ---------------- cos: mean-correct + cosine per pair ----------------
__global__ __launch_bounds__(256) void k_cos(
    const float* __restrict__ P, const float* __restrict__ asq,
    const float* __restrict__ sptm, const float* __restrict__ qrym,
    float* __restrict__ out)
{
  __shared__ float pred[4];
  __shared__ float MsMq[2];
  __shared__ float red[12];
  const int pair = blockIdx.x;
  const int q = pair / WAYT, w = pair % WAYT;
  const int t = threadIdx.x, wid = t >> 6;

  float pm = 0.f;
  if (t < 100) pm = asq[(size_t)pair*256 + t] * sptm[w*100 + t];
  else if (t >= 128 && t < 228) pm = asq[(size_t)pair*256 + t] * qrym[q*100 + (t - 128)];
  #pragma unroll
  for (int m = 1; m < 64; m <<= 1) pm += __shfl_xor(pm, m);
  if ((t & 63) == 0) pred[wid] = pm;
  __syncthreads();
  if (t == 0) MsMq[0] = pred[0] + pred[1];
  if (t == 1) MsMq[1] = pred[2] + pred[3];
  __syncthreads();
  const float Ms = MsMq[0], Mq = MsMq[1];

  float d0 = 0.f, d1 = 0.f, d2 = 0.f;
  for (int c = t; c < 640; c += 256){
    const float sp = P[(size_t)pair*1280 + c] - Ms;
    const float qp = P[(size_t)pair*1280 + 640 + c] - Mq;
    d0 += sp*qp; d1 += sp*sp; d2 += qp*qp;
  }
  #pragma unroll
  for (int m = 1; m < 64; m <<= 1){
    d0 += __shfl_xor(d0, m); d1 += __shfl_xor(d1, m); d2 += __shfl_xor(d2, m);
  }
  if ((t & 63) == 0){ red[wid*3+0] = d0; red[wid*3+1] = d1; red[wid*3+2] = d2; }
  __syncthreads();
  if (t == 0){
    float e0 = 0.f, e1 = 0.f, e2 = 0.f;
    #pragma unroll
    for (int k = 0; k < 4; k++){ e0 += red[k*3]; e1 += red[k*3+1]; e2 += red[k*3+2]; }
    const float den = fmaxf(sqrtf(e1), 1e-8f) * fmaxf(sqrtf(e2), 1e-8f);
    out[pair] = (e0 / den) * 5.0f;
  }
}

extern "C" void kernel_launch(void* const* d_in, const int* in_sizes, int n_in,
                              void* d_out, int out_size, void* d_ws, size_t ws_size,
                              hipStream_t stream)
{
  (void)in_sizes; (void)n_in; (void)out_size; (void)ws_size;
  const float* spt = (const float*)d_in[0];
  const float* qry = (const float*)d_in[1];
  const float* Wc  = (const float*)d_in[2];
  const float* gc  = (const float*)d_in[3];
  const float* bc  = (const float*)d_in[4];

  float* ws    = (float*)d_ws;
  float* cp    = ws;                          // 256
  float* wsum  = ws + 256;                    // 64
  float* sptm  = ws + 320;                    // 500
  float* qrym  = ws + 820;                    // 15000 -> pad 15872
  f16*  Apack  = (f16*)(ws + 15872);          // 2560 f16
  f16*  Wf2    = (f16*)(ws + 17152);          // 256 f16
  f16*  W65    = (f16*)(ws + 17408);          // 51200 f16
  f16*  MuF    = (f16*)(ws + 43008);          // 14336 f16
  f16*  MhF    = (f16*)(ws + 50176);          // 14336 f16
  f16*  s16    = (f16*)(ws + 57344);          // 35840 f16
  f16*  q16    = (f16*)(ws + 75264);          // 1075200 f16
  f16*  z      = (f16*)(ws + 612864);         // 7.5M f16
  f16*  F      = (f16*)(ws + 4362864);        // 7.5M f16
  f16*  spt16  = (f16*)(ws + 8112864);        // 409600 f16 (end ~33.3 MB)
  // aliases (lifetime-disjoint):
  float* asq   = ws + 75264;                  // over q16 (dead after k_z); 192000 f32
  f16*  asqh   = (f16*)(ws + 75264 + 192000); // over q16
  float* P     = ws + 612864;                 // over z (dead after k_l1); 960000 f32

  k_prep_all<<<241, 256, 0, stream>>>(
      spt, Wc,
      (const float*)d_in[5],  (const float*)d_in[6],  (const float*)d_in[7],
      (const float*)d_in[8],  (const float*)d_in[9],  (const float*)d_in[10],
      (const float*)d_in[11], (const float*)d_in[12], (const float*)d_in[13],
      (const float*)d_in[14], (const float*)d_in[15], (const float*)d_in[16],
      (const float*)d_in[17], (const float*)d_in[18], (const float*)d_in[19],
      (const float*)d_in[20], (const float*)d_in[21], (const float*)d_in[22],
      cp, Apack, Wf2, MuF, MhF, W65, wsum, spt16);
  k_feat<<<620, 256, 0, stream>>>(spt, qry, W65, wsum, gc, bc, s16, q16, sptm, qrym);
  k_z<<<NQT*WAYT, 256, 0, stream>>>(s16, q16, cp, MuF, MhF, z);
  {
    dim3 grid(10, NQT*WAYT);
    k_l1<<<grid, 256, 0, stream>>>(z, cp, Apack, Wf2, F);
  }
  k_attn_a<<<NQT*WAYT, 256, 0, stream>>>(F, asq, asqh);
  k_spqp<<<350, 256, 0, stream>>>(spt16, qry, asqh, P);
  k_cos<<<NQT*WAYT, 256, 0, stream>>>(P, asq, sptm, qrym, (float*)d_out);
}